// Round 1
// baseline (9421.590 us; speedup 1.0000x reference)
//
#include <hip/hip_runtime.h>

typedef unsigned short ushort_t;
typedef unsigned int uint32;
typedef __attribute__((ext_vector_type(4))) float f32x4;
typedef __attribute__((ext_vector_type(8))) short bf16x8;

#define B_   4
#define S_   2048
#define D_   1024
#define H_   16
#define HD_  64
#define DFF_ 4096
#define M_   (B_ * S_)          // 8192 rows (tokens)

#define RES_   0.28867513459481287f   // 1/sqrt(12)
#define SCALE_ 0.03125f               // 1/sqrt(1024)
#define EPS_   1e-5f

__device__ __forceinline__ ushort_t f2bf(float f) {
    union { float f; uint32 u; } c; c.f = f;
    uint32 u = c.u + 0x7fffu + ((c.u >> 16) & 1u);
    return (ushort_t)(u >> 16);
}
__device__ __forceinline__ float bf2f(ushort_t h) {
    union { uint32 u; float f; } c; c.u = ((uint32)h) << 16;
    return c.f;
}

// ---------------------------------------------------------------------------
// Transpose + fp32->bf16 cast:  W[K][N] (fp32, row-major) -> Wt[N][K] (bf16)
// ---------------------------------------------------------------------------
__global__ __launch_bounds__(256) void transpose_cast_kernel(
    const float* __restrict__ W, ushort_t* __restrict__ Wt, int K, int N)
{
    __shared__ float tile[32][33];
    const int bx = blockIdx.x * 32;  // N offset
    const int by = blockIdx.y * 32;  // K offset
    const int tx = threadIdx.x;      // 0..31
    const int ty = threadIdx.y;      // 0..7
    #pragma unroll
    for (int i = 0; i < 32; i += 8)
        tile[ty + i][tx] = W[(size_t)(by + ty + i) * N + bx + tx];
    __syncthreads();
    #pragma unroll
    for (int i = 0; i < 32; i += 8)
        Wt[(size_t)(bx + ty + i) * K + by + tx] = f2bf(tile[tx][ty + i]);
}

// ---------------------------------------------------------------------------
// Concat bq,bk,bv -> bqkv[3072]
// ---------------------------------------------------------------------------
__global__ void concat_bias_kernel(const float* __restrict__ bq,
                                   const float* __restrict__ bk,
                                   const float* __restrict__ bv,
                                   float* __restrict__ bqkv)
{
    int i = blockIdx.x * blockDim.x + threadIdx.x;
    if (i < 3 * D_) {
        float v = (i < D_) ? bq[i] : (i < 2 * D_) ? bk[i - D_] : bv[i - 2 * D_];
        bqkv[i] = v;
    }
}

// ---------------------------------------------------------------------------
// LayerNorm: fp32 in [rows][1024] -> bf16 out
// one block (256 thr) per row, 4 elements per thread
// ---------------------------------------------------------------------------
__global__ __launch_bounds__(256) void ln_kernel(
    const float* __restrict__ x, const float* __restrict__ g,
    const float* __restrict__ be, ushort_t* __restrict__ out)
{
    const int row = blockIdx.x;
    const int t = threadIdx.x;
    const int lane = t & 63;
    const int wave = t >> 6;
    const float4* xr = (const float4*)(x + (size_t)row * D_);
    float4 v = xr[t];
    float s  = v.x + v.y + v.z + v.w;
    float s2 = v.x * v.x + v.y * v.y + v.z * v.z + v.w * v.w;
    #pragma unroll
    for (int off = 32; off; off >>= 1) {
        s  += __shfl_xor(s, off);
        s2 += __shfl_xor(s2, off);
    }
    __shared__ float red[8];
    if (lane == 0) { red[wave * 2] = s; red[wave * 2 + 1] = s2; }
    __syncthreads();
    s  = red[0] + red[2] + red[4] + red[6];
    s2 = red[1] + red[3] + red[5] + red[7];
    const float mean = s * (1.0f / D_);
    const float var  = s2 * (1.0f / D_) - mean * mean;
    const float rstd = rsqrtf(var + EPS_);
    const float4 gv  = ((const float4*)g)[t];
    const float4 bv  = ((const float4*)be)[t];
    ushort_t o[4];
    o[0] = f2bf((v.x - mean) * rstd * gv.x + bv.x);
    o[1] = f2bf((v.y - mean) * rstd * gv.y + bv.y);
    o[2] = f2bf((v.z - mean) * rstd * gv.z + bv.z);
    o[3] = f2bf((v.w - mean) * rstd * gv.w + bv.w);
    *(ushort2*)&out[(size_t)row * D_ + t * 4]     = make_ushort2(o[0], o[1]);
    *(ushort2*)&out[(size_t)row * D_ + t * 4 + 2] = make_ushort2(o[2], o[3]);
}

// ---------------------------------------------------------------------------
// GEMM: C[M][N] = epilogue(A[M][K] @ Bt[N][K]^T + bias)
//   A, Bt bf16; acc fp32.
//   MODE 0: out bf16 = acc + bias
//   MODE 1: out bf16 = relu(acc + bias)
//   MODE 2: out fp32 = res + RES_ * (acc + bias)
// 128x128 tile, 4 waves (each 64x64 via 4x4 16x16x32 MFMA frags), BK=32,
// global_load_lds width-16 staging.
// ---------------------------------------------------------------------------
template <int MODE>
__global__ __launch_bounds__(256) void gemm_bt_kernel(
    const ushort_t* __restrict__ A, const ushort_t* __restrict__ Bt,
    const float* __restrict__ bias, const float* __restrict__ res,
    void* __restrict__ Cout, int M, int N, int K)
{
    __shared__ __align__(16) ushort_t As[128][32];
    __shared__ __align__(16) ushort_t Bs[128][32];

    const int tid  = threadIdx.x;
    const int wave = tid >> 6;
    const int lane = tid & 63;
    const int m0 = blockIdx.y * 128;
    const int n0 = blockIdx.x * 128;
    const int wm = (wave >> 1) * 64;
    const int wn = (wave & 1) * 64;

    // staging geometry: 8 chunks of 16 rows; wave w owns chunks 2w, 2w+1.
    // within a chunk: lane covers row = chunk*16 + lane/4, 16B col seg = lane%4
    const int chunk0 = wave * 2;
    const int rowIn  = chunk0 * 16 + (lane >> 2);
    const int colOff = (lane & 3) * 8;            // elements (8 bf16 = 16B)
    const ushort_t* Ab = A  + (size_t)(m0 + rowIn) * K + colOff;
    const ushort_t* Bb = Bt + (size_t)(n0 + rowIn) * K + colOff;
    ushort_t* lA = &As[0][0] + chunk0 * 512;      // 512 ushorts = 1024B per chunk
    ushort_t* lB = &Bs[0][0] + chunk0 * 512;

    f32x4 acc[4][4] = {};

    for (int k0 = 0; k0 < K; k0 += 32) {
        __builtin_amdgcn_global_load_lds(
            (const __attribute__((address_space(1))) void*)(Ab + k0),
            (__attribute__((address_space(3))) void*)(lA), 16, 0, 0);
        __builtin_amdgcn_global_load_lds(
            (const __attribute__((address_space(1))) void*)(Ab + (size_t)16 * K + k0),
            (__attribute__((address_space(3))) void*)(lA + 512), 16, 0, 0);
        __builtin_amdgcn_global_load_lds(
            (const __attribute__((address_space(1))) void*)(Bb + k0),
            (__attribute__((address_space(3))) void*)(lB), 16, 0, 0);
        __builtin_amdgcn_global_load_lds(
            (const __attribute__((address_space(1))) void*)(Bb + (size_t)16 * K + k0),
            (__attribute__((address_space(3))) void*)(lB + 512), 16, 0, 0);
        __syncthreads();

        bf16x8 af[4], bfr[4];
        #pragma unroll
        for (int mf = 0; mf < 4; ++mf)
            af[mf] = *(const bf16x8*)&As[wm + mf * 16 + (lane & 15)][(lane >> 4) * 8];
        #pragma unroll
        for (int nf = 0; nf < 4; ++nf)
            bfr[nf] = *(const bf16x8*)&Bs[wn + nf * 16 + (lane & 15)][(lane >> 4) * 8];
        #pragma unroll
        for (int mf = 0; mf < 4; ++mf)
            #pragma unroll
            for (int nf = 0; nf < 4; ++nf)
                acc[mf][nf] = __builtin_amdgcn_mfma_f32_16x16x32_bf16(
                    af[mf], bfr[nf], acc[mf][nf], 0, 0, 0);
        __syncthreads();
    }

    // epilogue: C/D layout col = lane&15, row = (lane>>4)*4 + r
    const int rbase = (lane >> 4) * 4;
    const int cbase = lane & 15;
    #pragma unroll
    for (int mf = 0; mf < 4; ++mf) {
        #pragma unroll
        for (int nf = 0; nf < 4; ++nf) {
            const int col = n0 + wn + nf * 16 + cbase;
            const float bcol = bias[col];
            #pragma unroll
            for (int r = 0; r < 4; ++r) {
                const int row = m0 + wm + mf * 16 + rbase + r;
                float v = acc[mf][nf][r] + bcol;
                const size_t idx = (size_t)row * N + col;
                if (MODE == 0) {
                    ((ushort_t*)Cout)[idx] = f2bf(v);
                } else if (MODE == 1) {
                    ((ushort_t*)Cout)[idx] = f2bf(fmaxf(v, 0.0f));
                } else {
                    ((float*)Cout)[idx] = res[idx] + RES_ * v;
                }
            }
        }
    }
}

// ---------------------------------------------------------------------------
// Causal attention from packed qkv (bf16 [8192][3072]):
// one wave per query row; lane = head dim (HD=64). Online softmax.
// out: bf16 [8192][1024]
// ---------------------------------------------------------------------------
__global__ __launch_bounds__(256) void attn_kernel(
    const ushort_t* __restrict__ qkv, ushort_t* __restrict__ out)
{
    const int lane = threadIdx.x & 63;
    const int wave = threadIdx.x >> 6;
    const int bh = blockIdx.y;
    const int b = bh >> 4;
    const int h = bh & 15;
    const int s = blockIdx.x * 4 + wave;

    const size_t tokQ = (size_t)(b * S_ + s) * (3 * D_);
    const float q = bf2f(qkv[tokQ + h * HD_ + lane]) * SCALE_;

    const ushort_t* Kb = qkv + (size_t)b * S_ * (3 * D_) + D_ + h * HD_ + lane;
    const ushort_t* Vb = Kb + D_;

    float m = -1e30f, l = 0.0f, acc = 0.0f;
    for (int k = 0; k <= s; ++k) {
        float d = q * bf2f(Kb[(size_t)k * (3 * D_)]);
        #pragma unroll
        for (int off = 32; off; off >>= 1) d += __shfl_xor(d, off);
        const float vv = bf2f(Vb[(size_t)k * (3 * D_)]);
        const float mn = fmaxf(m, d);
        const float c  = __expf(m - mn);
        const float p  = __expf(d - mn);
        l   = l * c + p;
        acc = acc * c + p * vv;
        m = mn;
    }
    out[(size_t)(b * S_ + s) * D_ + h * HD_ + lane] = f2bf(acc / l);
}

// ---------------------------------------------------------------------------
// launch
// ---------------------------------------------------------------------------
extern "C" void kernel_launch(void* const* d_in, const int* in_sizes, int n_in,
                              void* d_out, int out_size, void* d_ws, size_t ws_size,
                              hipStream_t stream)
{
    const float* x   = (const float*)d_in[0];
    const float* Wq  = (const float*)d_in[1];
    const float* bq  = (const float*)d_in[2];
    const float* Wk  = (const float*)d_in[3];
    const float* bk  = (const float*)d_in[4];
    const float* Wv  = (const float*)d_in[5];
    const float* bv  = (const float*)d_in[6];
    const float* Wo  = (const float*)d_in[7];
    const float* bo  = (const float*)d_in[8];
    const float* g1  = (const float*)d_in[9];
    const float* be1 = (const float*)d_in[10];
    const float* g2  = (const float*)d_in[11];
    const float* be2 = (const float*)d_in[12];
    const float* W1  = (const float*)d_in[13];
    const float* b1  = (const float*)d_in[14];
    const float* W2  = (const float*)d_in[15];
    const float* b2  = (const float*)d_in[16];
    float* out = (float*)d_out;

    char* ws = (char*)d_ws;
    size_t o = 0;
    auto alloc = [&](size_t bytes) { size_t r = o; o = (o + bytes + 255) & ~(size_t)255; return r; };
    ushort_t* Wqkvt = (ushort_t*)(ws + alloc((size_t)3 * D_ * D_ * 2));   // [3072][1024]
    ushort_t* Wot   = (ushort_t*)(ws + alloc((size_t)D_ * D_ * 2));      // [1024][1024]
    ushort_t* W1t   = (ushort_t*)(ws + alloc((size_t)DFF_ * D_ * 2));    // [4096][1024]
    ushort_t* W2t   = (ushort_t*)(ws + alloc((size_t)D_ * DFF_ * 2));    // [1024][4096]
    float*    bqkv  = (float*)(ws + alloc((size_t)3 * D_ * 4));
    ushort_t* lnbuf = (ushort_t*)(ws + alloc((size_t)M_ * D_ * 2));      // ln1 then ln2
    ushort_t* bigbuf= (ushort_t*)(ws + alloc((size_t)M_ * DFF_ * 2));    // qkv then ffn-hidden
    ushort_t* attnb = (ushort_t*)(ws + alloc((size_t)M_ * D_ * 2));
    float*    x1    = (float*)(ws + alloc((size_t)M_ * D_ * 4));

    dim3 tblock(32, 8);
    // weight transposes (fp32 -> bf16, [K][N] -> [N][K])
    transpose_cast_kernel<<<dim3(D_/32, D_/32), tblock, 0, stream>>>(Wq, Wqkvt,            D_, D_);
    transpose_cast_kernel<<<dim3(D_/32, D_/32), tblock, 0, stream>>>(Wk, Wqkvt + D_*D_,    D_, D_);
    transpose_cast_kernel<<<dim3(D_/32, D_/32), tblock, 0, stream>>>(Wv, Wqkvt + 2*D_*D_,  D_, D_);
    transpose_cast_kernel<<<dim3(D_/32, D_/32), tblock, 0, stream>>>(Wo, Wot,              D_, D_);
    transpose_cast_kernel<<<dim3(DFF_/32, D_/32), tblock, 0, stream>>>(W1, W1t,            D_, DFF_);
    transpose_cast_kernel<<<dim3(D_/32, DFF_/32), tblock, 0, stream>>>(W2, W2t,            DFF_, D_);
    concat_bias_kernel<<<12, 256, 0, stream>>>(bq, bk, bv, bqkv);

    // ln1
    ln_kernel<<<M_, 256, 0, stream>>>(x, g1, be1, lnbuf);
    // qkv = ln1 @ Wqkv + bqkv          [8192][3072] bf16
    gemm_bt_kernel<0><<<dim3(3*D_/128, M_/128), 256, 0, stream>>>(
        lnbuf, Wqkvt, bqkv, nullptr, bigbuf, M_, 3*D_, D_);
    // attention                         [8192][1024] bf16
    attn_kernel<<<dim3(S_/4, B_*H_), 256, 0, stream>>>(bigbuf, attnb);
    // x1 = x + RES*(attn @ Wo + bo)     [8192][1024] fp32
    gemm_bt_kernel<2><<<dim3(D_/128, M_/128), 256, 0, stream>>>(
        attnb, Wot, bo, x, x1, M_, D_, D_);
    // ln2
    ln_kernel<<<M_, 256, 0, stream>>>(x1, g2, be2, lnbuf);
    // ffh = relu(ln2 @ W1 + b1)         [8192][4096] bf16
    gemm_bt_kernel<1><<<dim3(DFF_/128, M_/128), 256, 0, stream>>>(
        lnbuf, W1t, b1, nullptr, bigbuf, M_, DFF_, D_);
    // out = x1 + RES*(ffh @ W2 + b2)    [8192][1024] fp32
    gemm_bt_kernel<2><<<dim3(D_/128, M_/128), 256, 0, stream>>>(
        bigbuf, W2t, b2, x1, out, M_, D_, DFF_);
}

// Round 2
// 597.884 us; speedup vs baseline: 15.7582x; 15.7582x over previous
//
#include <hip/hip_runtime.h>

typedef unsigned short ushort_t;
typedef unsigned int uint32;
typedef __attribute__((ext_vector_type(4))) float f32x4;
typedef __attribute__((ext_vector_type(8))) short bf16x8;

#define B_   4
#define S_   2048
#define D_   1024
#define H_   16
#define HD_  64
#define DFF_ 4096
#define M_   (B_ * S_)          // 8192 rows (tokens)

#define RES_   0.28867513459481287f   // 1/sqrt(12)
#define SCALE_ 0.03125f               // 1/sqrt(1024)
#define EPS_   1e-5f

__device__ __forceinline__ ushort_t f2bf(float f) {
    union { float f; uint32 u; } c; c.f = f;
    uint32 u = c.u + 0x7fffu + ((c.u >> 16) & 1u);
    return (ushort_t)(u >> 16);
}
__device__ __forceinline__ float bf2f(ushort_t h) {
    union { uint32 u; float f; } c; c.u = ((uint32)h) << 16;
    return c.f;
}

// ---------------------------------------------------------------------------
// Transpose + fp32->bf16 cast:  W[K][N] (fp32, row-major) -> Wt[N][K] (bf16)
// ---------------------------------------------------------------------------
__global__ __launch_bounds__(256) void transpose_cast_kernel(
    const float* __restrict__ W, ushort_t* __restrict__ Wt, int K, int N)
{
    __shared__ float tile[32][33];
    const int bx = blockIdx.x * 32;  // N offset
    const int by = blockIdx.y * 32;  // K offset
    const int tx = threadIdx.x;      // 0..31
    const int ty = threadIdx.y;      // 0..7
    #pragma unroll
    for (int i = 0; i < 32; i += 8)
        tile[ty + i][tx] = W[(size_t)(by + ty + i) * N + bx + tx];
    __syncthreads();
    #pragma unroll
    for (int i = 0; i < 32; i += 8)
        Wt[(size_t)(bx + ty + i) * K + by + tx] = f2bf(tile[tx][ty + i]);
}

// ---------------------------------------------------------------------------
// Concat bq,bk,bv -> bqkv[3072]
// ---------------------------------------------------------------------------
__global__ void concat_bias_kernel(const float* __restrict__ bq,
                                   const float* __restrict__ bk,
                                   const float* __restrict__ bv,
                                   float* __restrict__ bqkv)
{
    int i = blockIdx.x * blockDim.x + threadIdx.x;
    if (i < 3 * D_) {
        float v = (i < D_) ? bq[i] : (i < 2 * D_) ? bk[i - D_] : bv[i - 2 * D_];
        bqkv[i] = v;
    }
}

// ---------------------------------------------------------------------------
// LayerNorm: fp32 in [rows][1024] -> bf16 out
// ---------------------------------------------------------------------------
__global__ __launch_bounds__(256) void ln_kernel(
    const float* __restrict__ x, const float* __restrict__ g,
    const float* __restrict__ be, ushort_t* __restrict__ out)
{
    const int row = blockIdx.x;
    const int t = threadIdx.x;
    const int lane = t & 63;
    const int wave = t >> 6;
    const float4* xr = (const float4*)(x + (size_t)row * D_);
    float4 v = xr[t];
    float s  = v.x + v.y + v.z + v.w;
    float s2 = v.x * v.x + v.y * v.y + v.z * v.z + v.w * v.w;
    #pragma unroll
    for (int off = 32; off; off >>= 1) {
        s  += __shfl_xor(s, off);
        s2 += __shfl_xor(s2, off);
    }
    __shared__ float red[8];
    if (lane == 0) { red[wave * 2] = s; red[wave * 2 + 1] = s2; }
    __syncthreads();
    s  = red[0] + red[2] + red[4] + red[6];
    s2 = red[1] + red[3] + red[5] + red[7];
    const float mean = s * (1.0f / D_);
    const float var  = s2 * (1.0f / D_) - mean * mean;
    const float rstd = rsqrtf(var + EPS_);
    const float4 gv  = ((const float4*)g)[t];
    const float4 bv  = ((const float4*)be)[t];
    ushort_t o[4];
    o[0] = f2bf((v.x - mean) * rstd * gv.x + bv.x);
    o[1] = f2bf((v.y - mean) * rstd * gv.y + bv.y);
    o[2] = f2bf((v.z - mean) * rstd * gv.z + bv.z);
    o[3] = f2bf((v.w - mean) * rstd * gv.w + bv.w);
    *(ushort2*)&out[(size_t)row * D_ + t * 4]     = make_ushort2(o[0], o[1]);
    *(ushort2*)&out[(size_t)row * D_ + t * 4 + 2] = make_ushort2(o[2], o[3]);
}

// ---------------------------------------------------------------------------
// GEMM: C[M][N] = epilogue(A[M][K] @ Bt[N][K]^T + bias)
// ---------------------------------------------------------------------------
template <int MODE>
__global__ __launch_bounds__(256) void gemm_bt_kernel(
    const ushort_t* __restrict__ A, const ushort_t* __restrict__ Bt,
    const float* __restrict__ bias, const float* __restrict__ res,
    void* __restrict__ Cout, int M, int N, int K)
{
    __shared__ __align__(16) ushort_t As[128][32];
    __shared__ __align__(16) ushort_t Bs[128][32];

    const int tid  = threadIdx.x;
    const int wave = tid >> 6;
    const int lane = tid & 63;
    const int m0 = blockIdx.y * 128;
    const int n0 = blockIdx.x * 128;
    const int wm = (wave >> 1) * 64;
    const int wn = (wave & 1) * 64;

    const int chunk0 = wave * 2;
    const int rowIn  = chunk0 * 16 + (lane >> 2);
    const int colOff = (lane & 3) * 8;
    const ushort_t* Ab = A  + (size_t)(m0 + rowIn) * K + colOff;
    const ushort_t* Bb = Bt + (size_t)(n0 + rowIn) * K + colOff;
    ushort_t* lA = &As[0][0] + chunk0 * 512;
    ushort_t* lB = &Bs[0][0] + chunk0 * 512;

    f32x4 acc[4][4] = {};

    for (int k0 = 0; k0 < K; k0 += 32) {
        __builtin_amdgcn_global_load_lds(
            (const __attribute__((address_space(1))) void*)(Ab + k0),
            (__attribute__((address_space(3))) void*)(lA), 16, 0, 0);
        __builtin_amdgcn_global_load_lds(
            (const __attribute__((address_space(1))) void*)(Ab + (size_t)16 * K + k0),
            (__attribute__((address_space(3))) void*)(lA + 512), 16, 0, 0);
        __builtin_amdgcn_global_load_lds(
            (const __attribute__((address_space(1))) void*)(Bb + k0),
            (__attribute__((address_space(3))) void*)(lB), 16, 0, 0);
        __builtin_amdgcn_global_load_lds(
            (const __attribute__((address_space(1))) void*)(Bb + (size_t)16 * K + k0),
            (__attribute__((address_space(3))) void*)(lB + 512), 16, 0, 0);
        __syncthreads();

        bf16x8 af[4], bfr[4];
        #pragma unroll
        for (int mf = 0; mf < 4; ++mf)
            af[mf] = *(const bf16x8*)&As[wm + mf * 16 + (lane & 15)][(lane >> 4) * 8];
        #pragma unroll
        for (int nf = 0; nf < 4; ++nf)
            bfr[nf] = *(const bf16x8*)&Bs[wn + nf * 16 + (lane & 15)][(lane >> 4) * 8];
        #pragma unroll
        for (int mf = 0; mf < 4; ++mf)
            #pragma unroll
            for (int nf = 0; nf < 4; ++nf)
                acc[mf][nf] = __builtin_amdgcn_mfma_f32_16x16x32_bf16(
                    af[mf], bfr[nf], acc[mf][nf], 0, 0, 0);
        __syncthreads();
    }

    const int rbase = (lane >> 4) * 4;
    const int cbase = lane & 15;
    #pragma unroll
    for (int mf = 0; mf < 4; ++mf) {
        #pragma unroll
        for (int nf = 0; nf < 4; ++nf) {
            const int col = n0 + wn + nf * 16 + cbase;
            const float bcol = bias[col];
            #pragma unroll
            for (int r = 0; r < 4; ++r) {
                const int row = m0 + wm + mf * 16 + rbase + r;
                float v = acc[mf][nf][r] + bcol;
                const size_t idx = (size_t)row * N + col;
                if (MODE == 0) {
                    ((ushort_t*)Cout)[idx] = f2bf(v);
                } else if (MODE == 1) {
                    ((ushort_t*)Cout)[idx] = f2bf(fmaxf(v, 0.0f));
                } else {
                    ((float*)Cout)[idx] = res[idx] + RES_ * v;
                }
            }
        }
    }
}

// ---------------------------------------------------------------------------
// Flash attention (causal) from packed qkv (bf16 [8192][3072]).
// Block: 64 q-rows of one (b,h); 4 waves x 16 rows. KV blocks of 64.
// MFMA 16x16x32 for QK^T and PV. K/Vt/P staged in LDS with XOR chunk swizzle.
// out: bf16 [8192][1024]
// ---------------------------------------------------------------------------
__global__ __launch_bounds__(256) void fattn_kernel(
    const ushort_t* __restrict__ qkv, ushort_t* __restrict__ out)
{
    __shared__ __align__(16) ushort_t Ks[64 * 64];     // [key][d], chunk c^=key&7
    __shared__ __align__(16) ushort_t Vt[64 * 64];     // [d][key], chunk c^=(d&7)^((d>>3)&7)
    __shared__ __align__(16) ushort_t Ps[4][16 * 64];  // per-wave [q][key], chunk c^=q&7

    const int tid  = threadIdx.x;
    const int lane = tid & 63;
    const int wave = tid >> 6;
    const int bh = blockIdx.y;
    const int b = bh >> 4, h = bh & 15;
    const int qb = (S_ / 64 - 1) - blockIdx.x;   // longest blocks first
    const int q0 = qb * 64;

    const size_t rs = 3 * D_;
    const ushort_t* Qg = qkv + (size_t)b * S_ * rs + h * HD_;
    const ushort_t* Kg = Qg + D_;

    // Q fragments (A-operand): row = lane&15, k-offset = (lane>>4)*8 (+32 for kk=1)
    bf16x8 qf[2];
    {
        const int qr = q0 + wave * 16 + (lane & 15);
        const ushort_t* qp = Qg + (size_t)qr * rs + (lane >> 4) * 8;
        qf[0] = *(const bf16x8*)qp;
        qf[1] = *(const bf16x8*)(qp + 32);
    }

    float mrow[4] = {-1e30f, -1e30f, -1e30f, -1e30f};
    float lrow[4] = {0.f, 0.f, 0.f, 0.f};
    f32x4 oacc[4] = {};   // d-frags; element r = row (lane>>4)*4+r

    const int nkb = qb + 1;
    for (int kb = 0; kb < nkb; ++kb) {
        __syncthreads();   // protect prior-iter LDS reads
        // ---- stage K (swizzled) and V^T (swizzled) ----
        #pragma unroll
        for (int pass = 0; pass < 2; ++pass) {
            const int idx = pass * 256 + tid;      // 0..511
            const int key = idx >> 3, c = idx & 7;
            const ushort_t* src = Kg + (size_t)(kb * 64 + key) * rs + c * 8;
            bf16x8 kv = *(const bf16x8*)src;
            bf16x8 vv = *(const bf16x8*)(src + D_);
            *(bf16x8*)&Ks[key * 64 + ((c ^ (key & 7)) << 3)] = kv;
            #pragma unroll
            for (int j = 0; j < 8; ++j) {
                const int d  = c * 8 + j;
                const int cp = (key >> 3) ^ (d & 7) ^ ((d >> 3) & 7);
                Vt[d * 64 + (cp << 3) + (key & 7)] = (ushort_t)vv[j];
            }
        }
        __syncthreads();

        // ---- S = Q K^T (frags: row=q, col=key) ----
        f32x4 sf[4] = {};
        #pragma unroll
        for (int nf = 0; nf < 4; ++nf) {
            const int keyr = nf * 16 + (lane & 15);
            #pragma unroll
            for (int kk = 0; kk < 2; ++kk) {
                const int cc = kk * 4 + (lane >> 4);
                bf16x8 kf = *(const bf16x8*)&Ks[keyr * 64 + ((cc ^ (keyr & 7)) << 3)];
                sf[nf] = __builtin_amdgcn_mfma_f32_16x16x32_bf16(qf[kk], kf, sf[nf], 0, 0, 0);
            }
        }

        // ---- online softmax per row r ----
        const bool domask = (kb == nkb - 1);
        #pragma unroll
        for (int r = 0; r < 4; ++r) {
            const int row  = (lane >> 4) * 4 + r;
            const int qrow = q0 + wave * 16 + row;
            float s[4];
            float mx = -1e30f;
            #pragma unroll
            for (int nf = 0; nf < 4; ++nf) {
                float v = sf[nf][r] * SCALE_;
                if (domask && (kb * 64 + nf * 16 + (lane & 15)) > qrow) v = -1e30f;
                s[nf] = v;
                mx = fmaxf(mx, v);
            }
            #pragma unroll
            for (int off = 1; off < 16; off <<= 1) mx = fmaxf(mx, __shfl_xor(mx, off));
            const float mnew = fmaxf(mrow[r], mx);
            const float corr = __expf(mrow[r] - mnew);
            mrow[r] = mnew;
            float psum = 0.f;
            ushort_t pb[4];
            #pragma unroll
            for (int nf = 0; nf < 4; ++nf) {
                const float p = __expf(s[nf] - mnew);
                psum += p;
                pb[nf] = f2bf(p);
            }
            #pragma unroll
            for (int off = 1; off < 16; off <<= 1) psum += __shfl_xor(psum, off);
            lrow[r] = lrow[r] * corr + psum;
            #pragma unroll
            for (int nf = 0; nf < 4; ++nf) oacc[nf][r] *= corr;
            // write P[row][key] (bf16, swizzled)
            #pragma unroll
            for (int nf = 0; nf < 4; ++nf) {
                const int cc = nf * 2 + ((lane & 15) >> 3);
                Ps[wave][row * 64 + ((cc ^ (row & 7)) << 3) + (lane & 7)] = pb[nf];
            }
        }

        // ---- O += P V ----
        #pragma unroll
        for (int kk = 0; kk < 2; ++kk) {
            const int qr2 = lane & 15;
            const int cc  = kk * 4 + (lane >> 4);
            bf16x8 pa = *(const bf16x8*)&Ps[wave][qr2 * 64 + ((cc ^ (qr2 & 7)) << 3)];
            #pragma unroll
            for (int nf = 0; nf < 4; ++nf) {
                const int dr  = nf * 16 + (lane & 15);
                const int cvp = cc ^ (dr & 7) ^ ((dr >> 3) & 7);
                bf16x8 vf = *(const bf16x8*)&Vt[dr * 64 + (cvp << 3)];
                oacc[nf] = __builtin_amdgcn_mfma_f32_16x16x32_bf16(pa, vf, oacc[nf], 0, 0, 0);
            }
        }
    }

    // ---- epilogue: O = acc / l ----
    #pragma unroll
    for (int r = 0; r < 4; ++r) {
        const int q = q0 + wave * 16 + (lane >> 4) * 4 + r;
        const float inv = 1.0f / lrow[r];
        ushort_t* op = out + (size_t)(b * S_ + q) * D_ + h * HD_;
        #pragma unroll
        for (int nf = 0; nf < 4; ++nf)
            op[nf * 16 + (lane & 15)] = f2bf(oacc[nf][r] * inv);
    }
}

// ---------------------------------------------------------------------------
// launch
// ---------------------------------------------------------------------------
extern "C" void kernel_launch(void* const* d_in, const int* in_sizes, int n_in,
                              void* d_out, int out_size, void* d_ws, size_t ws_size,
                              hipStream_t stream)
{
    const float* x   = (const float*)d_in[0];
    const float* Wq  = (const float*)d_in[1];
    const float* bq  = (const float*)d_in[2];
    const float* Wk  = (const float*)d_in[3];
    const float* bk  = (const float*)d_in[4];
    const float* Wv  = (const float*)d_in[5];
    const float* bv  = (const float*)d_in[6];
    const float* Wo  = (const float*)d_in[7];
    const float* bo  = (const float*)d_in[8];
    const float* g1  = (const float*)d_in[9];
    const float* be1 = (const float*)d_in[10];
    const float* g2  = (const float*)d_in[11];
    const float* be2 = (const float*)d_in[12];
    const float* W1  = (const float*)d_in[13];
    const float* b1  = (const float*)d_in[14];
    const float* W2  = (const float*)d_in[15];
    const float* b2  = (const float*)d_in[16];
    float* out = (float*)d_out;

    char* ws = (char*)d_ws;
    size_t o = 0;
    auto alloc = [&](size_t bytes) { size_t r = o; o = (o + bytes + 255) & ~(size_t)255; return r; };
    ushort_t* Wqkvt = (ushort_t*)(ws + alloc((size_t)3 * D_ * D_ * 2));   // [3072][1024]
    ushort_t* Wot   = (ushort_t*)(ws + alloc((size_t)D_ * D_ * 2));      // [1024][1024]
    ushort_t* W1t   = (ushort_t*)(ws + alloc((size_t)DFF_ * D_ * 2));    // [4096][1024]
    ushort_t* W2t   = (ushort_t*)(ws + alloc((size_t)D_ * DFF_ * 2));    // [1024][4096]
    float*    bqkv  = (float*)(ws + alloc((size_t)3 * D_ * 4));
    ushort_t* lnbuf = (ushort_t*)(ws + alloc((size_t)M_ * D_ * 2));      // ln1 then ln2
    ushort_t* bigbuf= (ushort_t*)(ws + alloc((size_t)M_ * DFF_ * 2));    // qkv then ffn-hidden
    ushort_t* attnb = (ushort_t*)(ws + alloc((size_t)M_ * D_ * 2));
    float*    x1    = (float*)(ws + alloc((size_t)M_ * D_ * 4));

    dim3 tblock(32, 8);
    transpose_cast_kernel<<<dim3(D_/32, D_/32), tblock, 0, stream>>>(Wq, Wqkvt,            D_, D_);
    transpose_cast_kernel<<<dim3(D_/32, D_/32), tblock, 0, stream>>>(Wk, Wqkvt + D_*D_,    D_, D_);
    transpose_cast_kernel<<<dim3(D_/32, D_/32), tblock, 0, stream>>>(Wv, Wqkvt + 2*D_*D_,  D_, D_);
    transpose_cast_kernel<<<dim3(D_/32, D_/32), tblock, 0, stream>>>(Wo, Wot,              D_, D_);
    transpose_cast_kernel<<<dim3(DFF_/32, D_/32), tblock, 0, stream>>>(W1, W1t,            D_, DFF_);
    transpose_cast_kernel<<<dim3(D_/32, DFF_/32), tblock, 0, stream>>>(W2, W2t,            DFF_, D_);
    concat_bias_kernel<<<12, 256, 0, stream>>>(bq, bk, bv, bqkv);

    // ln1
    ln_kernel<<<M_, 256, 0, stream>>>(x, g1, be1, lnbuf);
    // qkv = ln1 @ Wqkv + bqkv          [8192][3072] bf16
    gemm_bt_kernel<0><<<dim3(3*D_/128, M_/128), 256, 0, stream>>>(
        lnbuf, Wqkvt, bqkv, nullptr, bigbuf, M_, 3*D_, D_);
    // flash attention                   [8192][1024] bf16
    fattn_kernel<<<dim3(S_/64, B_*H_), 256, 0, stream>>>(bigbuf, attnb);
    // x1 = x + RES*(attn @ Wo + bo)     [8192][1024] fp32
    gemm_bt_kernel<2><<<dim3(D_/128, M_/128), 256, 0, stream>>>(
        attnb, Wot, bo, x, x1, M_, D_, D_);
    // ln2
    ln_kernel<<<M_, 256, 0, stream>>>(x1, g2, be2, lnbuf);
    // ffh = relu(ln2 @ W1 + b1)         [8192][4096] bf16
    gemm_bt_kernel<1><<<dim3(DFF_/128, M_/128), 256, 0, stream>>>(
        lnbuf, W1t, b1, nullptr, bigbuf, M_, DFF_, D_);
    // out = x1 + RES*(ffh @ W2 + b2)    [8192][1024] fp32
    gemm_bt_kernel<2><<<dim3(D_/128, M_/128), 256, 0, stream>>>(
        bigbuf, W2t, b2, x1, out, M_, D_, DFF_);
}

// Round 3
// 513.786 us; speedup vs baseline: 18.3376x; 1.1637x over previous
//
#include <hip/hip_runtime.h>

typedef unsigned short ushort_t;
typedef unsigned int uint32;
typedef __attribute__((ext_vector_type(4))) float f32x4;
typedef __attribute__((ext_vector_type(8))) short bf16x8;

#define B_   4
#define S_   2048
#define D_   1024
#define H_   16
#define HD_  64
#define DFF_ 4096
#define M_   (B_ * S_)          // 8192 rows (tokens)

#define RES_   0.28867513459481287f   // 1/sqrt(12)
#define SCALE_ 0.03125f               // 1/sqrt(1024)
#define EPS_   1e-5f

__device__ __forceinline__ ushort_t f2bf(float f) {
    union { float f; uint32 u; } c; c.f = f;
    uint32 u = c.u + 0x7fffu + ((c.u >> 16) & 1u);
    return (ushort_t)(u >> 16);
}
__device__ __forceinline__ float bf2f(ushort_t h) {
    union { uint32 u; float f; } c; c.u = ((uint32)h) << 16;
    return c.f;
}

// ---------------------------------------------------------------------------
// Transpose + fp32->bf16 cast:  W[K][N] (fp32, row-major) -> Wt[N][K] (bf16)
// ---------------------------------------------------------------------------
__global__ __launch_bounds__(256) void transpose_cast_kernel(
    const float* __restrict__ W, ushort_t* __restrict__ Wt, int K, int N)
{
    __shared__ float tile[32][33];
    const int bx = blockIdx.x * 32;  // N offset
    const int by = blockIdx.y * 32;  // K offset
    const int tx = threadIdx.x;      // 0..31
    const int ty = threadIdx.y;      // 0..7
    #pragma unroll
    for (int i = 0; i < 32; i += 8)
        tile[ty + i][tx] = W[(size_t)(by + ty + i) * N + bx + tx];
    __syncthreads();
    #pragma unroll
    for (int i = 0; i < 32; i += 8)
        Wt[(size_t)(bx + ty + i) * K + by + tx] = f2bf(tile[tx][ty + i]);
}

// ---------------------------------------------------------------------------
// Concat bq,bk,bv -> bqkv[3072]
// ---------------------------------------------------------------------------
__global__ void concat_bias_kernel(const float* __restrict__ bq,
                                   const float* __restrict__ bk,
                                   const float* __restrict__ bv,
                                   float* __restrict__ bqkv)
{
    int i = blockIdx.x * blockDim.x + threadIdx.x;
    if (i < 3 * D_) {
        float v = (i < D_) ? bq[i] : (i < 2 * D_) ? bk[i - D_] : bv[i - 2 * D_];
        bqkv[i] = v;
    }
}

// ---------------------------------------------------------------------------
// LayerNorm: fp32 in [rows][1024] -> bf16 out
// ---------------------------------------------------------------------------
__global__ __launch_bounds__(256) void ln_kernel(
    const float* __restrict__ x, const float* __restrict__ g,
    const float* __restrict__ be, ushort_t* __restrict__ out)
{
    const int row = blockIdx.x;
    const int t = threadIdx.x;
    const int lane = t & 63;
    const int wave = t >> 6;
    const float4* xr = (const float4*)(x + (size_t)row * D_);
    float4 v = xr[t];
    float s  = v.x + v.y + v.z + v.w;
    float s2 = v.x * v.x + v.y * v.y + v.z * v.z + v.w * v.w;
    #pragma unroll
    for (int off = 32; off; off >>= 1) {
        s  += __shfl_xor(s, off);
        s2 += __shfl_xor(s2, off);
    }
    __shared__ float red[8];
    if (lane == 0) { red[wave * 2] = s; red[wave * 2 + 1] = s2; }
    __syncthreads();
    s  = red[0] + red[2] + red[4] + red[6];
    s2 = red[1] + red[3] + red[5] + red[7];
    const float mean = s * (1.0f / D_);
    const float var  = s2 * (1.0f / D_) - mean * mean;
    const float rstd = rsqrtf(var + EPS_);
    const float4 gv  = ((const float4*)g)[t];
    const float4 bv  = ((const float4*)be)[t];
    ushort_t o[4];
    o[0] = f2bf((v.x - mean) * rstd * gv.x + bv.x);
    o[1] = f2bf((v.y - mean) * rstd * gv.y + bv.y);
    o[2] = f2bf((v.z - mean) * rstd * gv.z + bv.z);
    o[3] = f2bf((v.w - mean) * rstd * gv.w + bv.w);
    *(ushort2*)&out[(size_t)row * D_ + t * 4]     = make_ushort2(o[0], o[1]);
    *(ushort2*)&out[(size_t)row * D_ + t * 4 + 2] = make_ushort2(o[2], o[3]);
}

// ---------------------------------------------------------------------------
// GEMM: C[M][N] = epilogue(A[M][K] @ Bt[N][K]^T + bias)
// ---------------------------------------------------------------------------
template <int MODE>
__global__ __launch_bounds__(256) void gemm_bt_kernel(
    const ushort_t* __restrict__ A, const ushort_t* __restrict__ Bt,
    const float* __restrict__ bias, const float* __restrict__ res,
    void* __restrict__ Cout, int M, int N, int K)
{
    __shared__ __align__(16) ushort_t As[128][32];
    __shared__ __align__(16) ushort_t Bs[128][32];

    const int tid  = threadIdx.x;
    const int wave = tid >> 6;
    const int lane = tid & 63;
    const int m0 = blockIdx.y * 128;
    const int n0 = blockIdx.x * 128;
    const int wm = (wave >> 1) * 64;
    const int wn = (wave & 1) * 64;

    const int chunk0 = wave * 2;
    const int rowIn  = chunk0 * 16 + (lane >> 2);
    const int colOff = (lane & 3) * 8;
    const ushort_t* Ab = A  + (size_t)(m0 + rowIn) * K + colOff;
    const ushort_t* Bb = Bt + (size_t)(n0 + rowIn) * K + colOff;
    ushort_t* lA = &As[0][0] + chunk0 * 512;
    ushort_t* lB = &Bs[0][0] + chunk0 * 512;

    f32x4 acc[4][4] = {};

    for (int k0 = 0; k0 < K; k0 += 32) {
        __builtin_amdgcn_global_load_lds(
            (const __attribute__((address_space(1))) void*)(Ab + k0),
            (__attribute__((address_space(3))) void*)(lA), 16, 0, 0);
        __builtin_amdgcn_global_load_lds(
            (const __attribute__((address_space(1))) void*)(Ab + (size_t)16 * K + k0),
            (__attribute__((address_space(3))) void*)(lA + 512), 16, 0, 0);
        __builtin_amdgcn_global_load_lds(
            (const __attribute__((address_space(1))) void*)(Bb + k0),
            (__attribute__((address_space(3))) void*)(lB), 16, 0, 0);
        __builtin_amdgcn_global_load_lds(
            (const __attribute__((address_space(1))) void*)(Bb + (size_t)16 * K + k0),
            (__attribute__((address_space(3))) void*)(lB + 512), 16, 0, 0);
        __syncthreads();

        bf16x8 af[4], bfr[4];
        #pragma unroll
        for (int mf = 0; mf < 4; ++mf)
            af[mf] = *(const bf16x8*)&As[wm + mf * 16 + (lane & 15)][(lane >> 4) * 8];
        #pragma unroll
        for (int nf = 0; nf < 4; ++nf)
            bfr[nf] = *(const bf16x8*)&Bs[wn + nf * 16 + (lane & 15)][(lane >> 4) * 8];
        #pragma unroll
        for (int mf = 0; mf < 4; ++mf)
            #pragma unroll
            for (int nf = 0; nf < 4; ++nf)
                acc[mf][nf] = __builtin_amdgcn_mfma_f32_16x16x32_bf16(
                    af[mf], bfr[nf], acc[mf][nf], 0, 0, 0);
        __syncthreads();
    }

    const int rbase = (lane >> 4) * 4;
    const int cbase = lane & 15;
    #pragma unroll
    for (int mf = 0; mf < 4; ++mf) {
        #pragma unroll
        for (int nf = 0; nf < 4; ++nf) {
            const int col = n0 + wn + nf * 16 + cbase;
            const float bcol = bias[col];
            #pragma unroll
            for (int r = 0; r < 4; ++r) {
                const int row = m0 + wm + mf * 16 + rbase + r;
                float v = acc[mf][nf][r] + bcol;
                const size_t idx = (size_t)row * N + col;
                if (MODE == 0) {
                    ((ushort_t*)Cout)[idx] = f2bf(v);
                } else if (MODE == 1) {
                    ((ushort_t*)Cout)[idx] = f2bf(fmaxf(v, 0.0f));
                } else {
                    ((float*)Cout)[idx] = res[idx] + RES_ * v;
                }
            }
        }
    }
}

// ---------------------------------------------------------------------------
// Flash attention v3 (causal) from packed qkv (bf16 [8192][3072]).
// Block: 128 q-rows of one (b,h); 4 waves x 32 rows (2 q-groups of 16).
// Swapped QK^T (mfma(K,Q) -> S^T[key][q]) => lane-local softmax rows,
// 2-shfl reduces, packed b64 P writes. Deferred-max rescale (THR=8).
// out: bf16 [8192][1024]
// ---------------------------------------------------------------------------
__global__ __launch_bounds__(256) void fattn_kernel(
    const ushort_t* __restrict__ qkv, ushort_t* __restrict__ out)
{
    __shared__ __align__(16) ushort_t Ks[64 * 64];     // [key][d], chunk c^=key&7
    __shared__ __align__(16) ushort_t Vt[64 * 64];     // [d][key], chunk c^=(d&7)^((d>>3)&7)
    __shared__ __align__(16) ushort_t Ps[4][32 * 64];  // per-wave [q][key], 16B-chunk c16^=q&7

    const int tid  = threadIdx.x;
    const int lane = tid & 63;
    const int w    = tid >> 6;
    const int bh = blockIdx.y;
    const int b = bh >> 4, h = bh & 15;
    const int qt = (S_ / 128 - 1) - blockIdx.x;   // longest blocks first
    const int q0 = qt * 128;

    const int l15 = lane & 15;
    const int g   = lane >> 4;

    const size_t rs = 3 * D_;
    const ushort_t* Qg = qkv + (size_t)b * S_ * rs + h * HD_;
    const ushort_t* Kg = Qg + D_;

    // Q B-frags (col=q=l15, k=(g)*8+e +kk*32), pre-scaled by SCALE_ (2^-5: exact)
    bf16x8 qf[2][2];
    #pragma unroll
    for (int qg = 0; qg < 2; ++qg) {
        const int qrow = q0 + w * 32 + qg * 16 + l15;
        #pragma unroll
        for (int kk = 0; kk < 2; ++kk) {
            bf16x8 t = *(const bf16x8*)(Qg + (size_t)qrow * rs + kk * 32 + g * 8);
            #pragma unroll
            for (int e = 0; e < 8; ++e)
                t[e] = (short)f2bf(bf2f((ushort_t)t[e]) * SCALE_);
            qf[qg][kk] = t;
        }
    }

    float mrow[2] = {-1e30f, -1e30f};
    float lrow[2] = {0.f, 0.f};
    f32x4 oacc[2][4] = {};   // [qg][d-frag]; D: col=d=l15, row(q-local)=g*4+r

    const int nkb = 2 * qt + 2;
    for (int kb = 0; kb < nkb; ++kb) {
        __syncthreads();   // protect prior-iter K/Vt reads
        // ---- stage K (swizzled) and V^T (swizzled) ----
        #pragma unroll
        for (int pass = 0; pass < 2; ++pass) {
            const int idx = pass * 256 + tid;      // 0..511
            const int key = idx >> 3, c = idx & 7;
            const ushort_t* src = Kg + (size_t)(kb * 64 + key) * rs + c * 8;
            bf16x8 kv = *(const bf16x8*)src;
            bf16x8 vv = *(const bf16x8*)(src + D_);
            *(bf16x8*)&Ks[key * 64 + ((c ^ (key & 7)) << 3)] = kv;
            #pragma unroll
            for (int j = 0; j < 8; ++j) {
                const int d  = c * 8 + j;
                const int cp = (key >> 3) ^ (d & 7) ^ ((d >> 3) & 7);
                Vt[d * 64 + (cp << 3) + (key & 7)] = (ushort_t)vv[j];
            }
        }
        __syncthreads();

        // ---- S^T = K Q^T (D[key][q]: col=q=l15, row=key=g*4+r) ----
        f32x4 sf[2][4] = {};
        #pragma unroll
        for (int kk = 0; kk < 2; ++kk) {
            const int cc = kk * 4 + g;
            #pragma unroll
            for (int nf = 0; nf < 4; ++nf) {
                const int keyr = nf * 16 + l15;
                bf16x8 kf = *(const bf16x8*)&Ks[keyr * 64 + ((cc ^ (keyr & 7)) << 3)];
                sf[0][nf] = __builtin_amdgcn_mfma_f32_16x16x32_bf16(kf, qf[0][kk], sf[0][nf], 0, 0, 0);
                sf[1][nf] = __builtin_amdgcn_mfma_f32_16x16x32_bf16(kf, qf[1][kk], sf[1][nf], 0, 0, 0);
            }
        }

        // ---- mask + per-row max (lane owns q-row q0+w*32+qg*16+l15) ----
        float pm[2];
        #pragma unroll
        for (int qg = 0; qg < 2; ++qg) {
            const int qbase = q0 + w * 32 + qg * 16;
            if (kb * 64 + 63 > qbase) {           // wave-uniform guard
                const int q = qbase + l15;
                #pragma unroll
                for (int nf = 0; nf < 4; ++nf)
                    #pragma unroll
                    for (int r = 0; r < 4; ++r)
                        if (kb * 64 + nf * 16 + g * 4 + r > q) sf[qg][nf][r] = -1e30f;
            }
            float mx = -1e30f;
            #pragma unroll
            for (int nf = 0; nf < 4; ++nf)
                #pragma unroll
                for (int r = 0; r < 4; ++r) mx = fmaxf(mx, sf[qg][nf][r]);
            mx = fmaxf(mx, __shfl_xor(mx, 16));
            mx = fmaxf(mx, __shfl_xor(mx, 32));
            pm[qg] = mx;
        }

        // ---- deferred-max rescale (T13, THR=8) ----
        const int ok = ((pm[0] - mrow[0]) <= 8.0f) & ((pm[1] - mrow[1]) <= 8.0f);
        if (!__all(ok)) {
            #pragma unroll
            for (int qg = 0; qg < 2; ++qg) {
                const float mnew = fmaxf(mrow[qg], pm[qg]);
                const float corr = __expf(mrow[qg] - mnew);
                mrow[qg] = mnew;
                lrow[qg] *= corr;
                #pragma unroll
                for (int r = 0; r < 4; ++r) {
                    const float cr = __shfl(corr, g * 4 + r, 16);
                    #pragma unroll
                    for (int nf = 0; nf < 4; ++nf) oacc[qg][nf][r] *= cr;
                }
            }
        }

        // ---- P = exp(S - m), row-sum, packed write to Ps ----
        #pragma unroll
        for (int qg = 0; qg < 2; ++qg) {
            const int qrow = qg * 16 + l15;       // local row 0..31
            float psum = 0.f;
            #pragma unroll
            for (int nf = 0; nf < 4; ++nf) {
                const float p0 = __expf(sf[qg][nf][0] - mrow[qg]);
                const float p1 = __expf(sf[qg][nf][1] - mrow[qg]);
                const float p2 = __expf(sf[qg][nf][2] - mrow[qg]);
                const float p3 = __expf(sf[qg][nf][3] - mrow[qg]);
                psum += (p0 + p1) + (p2 + p3);
                ushort4 pk = make_ushort4(f2bf(p0), f2bf(p1), f2bf(p2), f2bf(p3));
                const int c16 = ((nf << 1) + (g >> 1)) ^ (qrow & 7);
                *(ushort4*)((char*)Ps[w] + qrow * 128 + c16 * 16 + (g & 1) * 8) = pk;
            }
            psum += __shfl_xor(psum, 16);
            psum += __shfl_xor(psum, 32);
            lrow[qg] += psum;
        }

        // ---- O += P V (A=P from Ps, B=V^T from Vt) ----
        #pragma unroll
        for (int kk = 0; kk < 2; ++kk) {
            const int cc = kk * 4 + g;
            bf16x8 pa[2];
            #pragma unroll
            for (int qg = 0; qg < 2; ++qg) {
                const int qrow = qg * 16 + l15;
                const int c16 = (kk * 4 + g) ^ (qrow & 7);
                pa[qg] = *(const bf16x8*)((const char*)Ps[w] + qrow * 128 + c16 * 16);
            }
            #pragma unroll
            for (int nf = 0; nf < 4; ++nf) {
                const int dr  = nf * 16 + l15;
                const int cvp = cc ^ (dr & 7) ^ ((dr >> 3) & 7);
                bf16x8 vf = *(const bf16x8*)&Vt[dr * 64 + (cvp << 3)];
                oacc[0][nf] = __builtin_amdgcn_mfma_f32_16x16x32_bf16(pa[0], vf, oacc[0][nf], 0, 0, 0);
                oacc[1][nf] = __builtin_amdgcn_mfma_f32_16x16x32_bf16(pa[1], vf, oacc[1][nf], 0, 0, 0);
            }
        }
    }

    // ---- epilogue: O = acc / l (l lives at lane l15=row; broadcast via shfl) ----
    #pragma unroll
    for (int qg = 0; qg < 2; ++qg) {
        const float linv = 1.0f / lrow[qg];
        #pragma unroll
        for (int r = 0; r < 4; ++r) {
            const float li = __shfl(linv, g * 4 + r, 16);
            const int q = q0 + w * 32 + qg * 16 + g * 4 + r;
            ushort_t* op = out + (size_t)(b * S_ + q) * D_ + h * HD_;
            #pragma unroll
            for (int nf = 0; nf < 4; ++nf)
                op[nf * 16 + l15] = f2bf(oacc[qg][nf][r] * li);
        }
    }
}

// ---------------------------------------------------------------------------
// launch
// ---------------------------------------------------------------------------
extern "C" void kernel_launch(void* const* d_in, const int* in_sizes, int n_in,
                              void* d_out, int out_size, void* d_ws, size_t ws_size,
                              hipStream_t stream)
{
    const float* x   = (const float*)d_in[0];
    const float* Wq  = (const float*)d_in[1];
    const float* bq  = (const float*)d_in[2];
    const float* Wk  = (const float*)d_in[3];
    const float* bk  = (const float*)d_in[4];
    const float* Wv  = (const float*)d_in[5];
    const float* bv  = (const float*)d_in[6];
    const float* Wo  = (const float*)d_in[7];
    const float* bo  = (const float*)d_in[8];
    const float* g1  = (const float*)d_in[9];
    const float* be1 = (const float*)d_in[10];
    const float* g2  = (const float*)d_in[11];
    const float* be2 = (const float*)d_in[12];
    const float* W1  = (const float*)d_in[13];
    const float* b1  = (const float*)d_in[14];
    const float* W2  = (const float*)d_in[15];
    const float* b2  = (const float*)d_in[16];
    float* out = (float*)d_out;

    char* ws = (char*)d_ws;
    size_t o = 0;
    auto alloc = [&](size_t bytes) { size_t r = o; o = (o + bytes + 255) & ~(size_t)255; return r; };
    ushort_t* Wqkvt = (ushort_t*)(ws + alloc((size_t)3 * D_ * D_ * 2));   // [3072][1024]
    ushort_t* Wot   = (ushort_t*)(ws + alloc((size_t)D_ * D_ * 2));      // [1024][1024]
    ushort_t* W1t   = (ushort_t*)(ws + alloc((size_t)DFF_ * D_ * 2));    // [4096][1024]
    ushort_t* W2t   = (ushort_t*)(ws + alloc((size_t)D_ * DFF_ * 2));    // [1024][4096]
    float*    bqkv  = (float*)(ws + alloc((size_t)3 * D_ * 4));
    ushort_t* lnbuf = (ushort_t*)(ws + alloc((size_t)M_ * D_ * 2));      // ln1 then ln2
    ushort_t* bigbuf= (ushort_t*)(ws + alloc((size_t)M_ * DFF_ * 2));    // qkv then ffn-hidden
    ushort_t* attnb = (ushort_t*)(ws + alloc((size_t)M_ * D_ * 2));
    float*    x1    = (float*)(ws + alloc((size_t)M_ * D_ * 4));

    dim3 tblock(32, 8);
    transpose_cast_kernel<<<dim3(D_/32, D_/32), tblock, 0, stream>>>(Wq, Wqkvt,            D_, D_);
    transpose_cast_kernel<<<dim3(D_/32, D_/32), tblock, 0, stream>>>(Wk, Wqkvt + D_*D_,    D_, D_);
    transpose_cast_kernel<<<dim3(D_/32, D_/32), tblock, 0, stream>>>(Wv, Wqkvt + 2*D_*D_,  D_, D_);
    transpose_cast_kernel<<<dim3(D_/32, D_/32), tblock, 0, stream>>>(Wo, Wot,              D_, D_);
    transpose_cast_kernel<<<dim3(DFF_/32, D_/32), tblock, 0, stream>>>(W1, W1t,            D_, DFF_);
    transpose_cast_kernel<<<dim3(D_/32, DFF_/32), tblock, 0, stream>>>(W2, W2t,            DFF_, D_);
    concat_bias_kernel<<<12, 256, 0, stream>>>(bq, bk, bv, bqkv);

    // ln1
    ln_kernel<<<M_, 256, 0, stream>>>(x, g1, be1, lnbuf);
    // qkv = ln1 @ Wqkv + bqkv          [8192][3072] bf16
    gemm_bt_kernel<0><<<dim3(3*D_/128, M_/128), 256, 0, stream>>>(
        lnbuf, Wqkvt, bqkv, nullptr, bigbuf, M_, 3*D_, D_);
    // flash attention                   [8192][1024] bf16
    fattn_kernel<<<dim3(S_/128, B_*H_), 256, 0, stream>>>(bigbuf, attnb);
    // x1 = x + RES*(attn @ Wo + bo)     [8192][1024] fp32
    gemm_bt_kernel<2><<<dim3(D_/128, M_/128), 256, 0, stream>>>(
        attnb, Wot, bo, x, x1, M_, D_, D_);
    // ln2
    ln_kernel<<<M_, 256, 0, stream>>>(x1, g2, be2, lnbuf);
    // ffh = relu(ln2 @ W1 + b1)         [8192][4096] bf16
    gemm_bt_kernel<1><<<dim3(DFF_/128, M_/128), 256, 0, stream>>>(
        lnbuf, W1t, b1, nullptr, bigbuf, M_, DFF_, D_);
    // out = x1 + RES*(ffh @ W2 + b2)    [8192][1024] fp32
    gemm_bt_kernel<2><<<dim3(D_/128, M_/128), 256, 0, stream>>>(
        bigbuf, W2t, b2, x1, out, M_, D_, DFF_);
}

// Round 4
// 470.230 us; speedup vs baseline: 20.0361x; 1.0926x over previous
//
#include <hip/hip_runtime.h>

typedef unsigned short ushort_t;
typedef unsigned int uint32;
typedef __attribute__((ext_vector_type(4))) float f32x4;
typedef __attribute__((ext_vector_type(8))) short bf16x8;

#define B_   4
#define S_   2048
#define D_   1024
#define H_   16
#define HD_  64
#define DFF_ 4096
#define M_   (B_ * S_)          // 8192 rows (tokens)

#define RES_   0.28867513459481287f   // 1/sqrt(12)
#define SCALE_ 0.03125f               // 1/sqrt(1024)
#define EPS_   1e-5f
#define LOG2E_ 1.4426950408889634f

__device__ __forceinline__ ushort_t f2bf(float f) {
    union { float f; uint32 u; } c; c.f = f;
    uint32 u = c.u + 0x7fffu + ((c.u >> 16) & 1u);
    return (ushort_t)(u >> 16);
}
__device__ __forceinline__ float bf2f(ushort_t h) {
    union { uint32 u; float f; } c; c.u = ((uint32)h) << 16;
    return c.f;
}
__device__ __forceinline__ float fexp2(float x) {
#if __has_builtin(__builtin_amdgcn_exp2f)
    return __builtin_amdgcn_exp2f(x);
#else
    float r; asm("v_exp_f32 %0, %1" : "=v"(r) : "v"(x)); return r;
#endif
}
__device__ __forceinline__ uint32 cvt_pk_bf16(float lo, float hi) {
    uint32 r;
    asm("v_cvt_pk_bf16_f32 %0, %1, %2" : "=v"(r) : "v"(lo), "v"(hi));
    return r;
}

// ---------------------------------------------------------------------------
// Transpose + fp32->bf16 cast:  W[K][N] (fp32, row-major) -> Wt[N][K] (bf16)
// ---------------------------------------------------------------------------
__global__ __launch_bounds__(256) void transpose_cast_kernel(
    const float* __restrict__ W, ushort_t* __restrict__ Wt, int K, int N)
{
    __shared__ float tile[32][33];
    const int bx = blockIdx.x * 32;  // N offset
    const int by = blockIdx.y * 32;  // K offset
    const int tx = threadIdx.x;      // 0..31
    const int ty = threadIdx.y;      // 0..7
    #pragma unroll
    for (int i = 0; i < 32; i += 8)
        tile[ty + i][tx] = W[(size_t)(by + ty + i) * N + bx + tx];
    __syncthreads();
    #pragma unroll
    for (int i = 0; i < 32; i += 8)
        Wt[(size_t)(bx + ty + i) * K + by + tx] = f2bf(tile[tx][ty + i]);
}

// ---------------------------------------------------------------------------
// Concat bq,bk,bv -> bqkv[3072]
// ---------------------------------------------------------------------------
__global__ void concat_bias_kernel(const float* __restrict__ bq,
                                   const float* __restrict__ bk,
                                   const float* __restrict__ bv,
                                   float* __restrict__ bqkv)
{
    int i = blockIdx.x * blockDim.x + threadIdx.x;
    if (i < 3 * D_) {
        float v = (i < D_) ? bq[i] : (i < 2 * D_) ? bk[i - D_] : bv[i - 2 * D_];
        bqkv[i] = v;
    }
}

// ---------------------------------------------------------------------------
// LayerNorm: fp32 in [rows][1024] -> bf16 out
// ---------------------------------------------------------------------------
__global__ __launch_bounds__(256) void ln_kernel(
    const float* __restrict__ x, const float* __restrict__ g,
    const float* __restrict__ be, ushort_t* __restrict__ out)
{
    const int row = blockIdx.x;
    const int t = threadIdx.x;
    const int lane = t & 63;
    const int wave = t >> 6;
    const float4* xr = (const float4*)(x + (size_t)row * D_);
    float4 v = xr[t];
    float s  = v.x + v.y + v.z + v.w;
    float s2 = v.x * v.x + v.y * v.y + v.z * v.z + v.w * v.w;
    #pragma unroll
    for (int off = 32; off; off >>= 1) {
        s  += __shfl_xor(s, off);
        s2 += __shfl_xor(s2, off);
    }
    __shared__ float red[8];
    if (lane == 0) { red[wave * 2] = s; red[wave * 2 + 1] = s2; }
    __syncthreads();
    s  = red[0] + red[2] + red[4] + red[6];
    s2 = red[1] + red[3] + red[5] + red[7];
    const float mean = s * (1.0f / D_);
    const float var  = s2 * (1.0f / D_) - mean * mean;
    const float rstd = rsqrtf(var + EPS_);
    const float4 gv  = ((const float4*)g)[t];
    const float4 bv  = ((const float4*)be)[t];
    ushort_t o[4];
    o[0] = f2bf((v.x - mean) * rstd * gv.x + bv.x);
    o[1] = f2bf((v.y - mean) * rstd * gv.y + bv.y);
    o[2] = f2bf((v.z - mean) * rstd * gv.z + bv.z);
    o[3] = f2bf((v.w - mean) * rstd * gv.w + bv.w);
    *(ushort2*)&out[(size_t)row * D_ + t * 4]     = make_ushort2(o[0], o[1]);
    *(ushort2*)&out[(size_t)row * D_ + t * 4 + 2] = make_ushort2(o[2], o[3]);
}

// ---------------------------------------------------------------------------
// GEMM: C[M][N] = epilogue(A[M][K] @ Bt[N][K]^T + bias)
// ---------------------------------------------------------------------------
template <int MODE>
__global__ __launch_bounds__(256) void gemm_bt_kernel(
    const ushort_t* __restrict__ A, const ushort_t* __restrict__ Bt,
    const float* __restrict__ bias, const float* __restrict__ res,
    void* __restrict__ Cout, int M, int N, int K)
{
    __shared__ __align__(16) ushort_t As[128][32];
    __shared__ __align__(16) ushort_t Bs[128][32];

    const int tid  = threadIdx.x;
    const int wave = tid >> 6;
    const int lane = tid & 63;
    const int m0 = blockIdx.y * 128;
    const int n0 = blockIdx.x * 128;
    const int wm = (wave >> 1) * 64;
    const int wn = (wave & 1) * 64;

    const int chunk0 = wave * 2;
    const int rowIn  = chunk0 * 16 + (lane >> 2);
    const int colOff = (lane & 3) * 8;
    const ushort_t* Ab = A  + (size_t)(m0 + rowIn) * K + colOff;
    const ushort_t* Bb = Bt + (size_t)(n0 + rowIn) * K + colOff;
    ushort_t* lA = &As[0][0] + chunk0 * 512;
    ushort_t* lB = &Bs[0][0] + chunk0 * 512;

    f32x4 acc[4][4] = {};

    for (int k0 = 0; k0 < K; k0 += 32) {
        __builtin_amdgcn_global_load_lds(
            (const __attribute__((address_space(1))) void*)(Ab + k0),
            (__attribute__((address_space(3))) void*)(lA), 16, 0, 0);
        __builtin_amdgcn_global_load_lds(
            (const __attribute__((address_space(1))) void*)(Ab + (size_t)16 * K + k0),
            (__attribute__((address_space(3))) void*)(lA + 512), 16, 0, 0);
        __builtin_amdgcn_global_load_lds(
            (const __attribute__((address_space(1))) void*)(Bb + k0),
            (__attribute__((address_space(3))) void*)(lB), 16, 0, 0);
        __builtin_amdgcn_global_load_lds(
            (const __attribute__((address_space(1))) void*)(Bb + (size_t)16 * K + k0),
            (__attribute__((address_space(3))) void*)(lB + 512), 16, 0, 0);
        __syncthreads();

        bf16x8 af[4], bfr[4];
        #pragma unroll
        for (int mf = 0; mf < 4; ++mf)
            af[mf] = *(const bf16x8*)&As[wm + mf * 16 + (lane & 15)][(lane >> 4) * 8];
        #pragma unroll
        for (int nf = 0; nf < 4; ++nf)
            bfr[nf] = *(const bf16x8*)&Bs[wn + nf * 16 + (lane & 15)][(lane >> 4) * 8];
        #pragma unroll
        for (int mf = 0; mf < 4; ++mf)
            #pragma unroll
            for (int nf = 0; nf < 4; ++nf)
                acc[mf][nf] = __builtin_amdgcn_mfma_f32_16x16x32_bf16(
                    af[mf], bfr[nf], acc[mf][nf], 0, 0, 0);
        __syncthreads();
    }

    const int rbase = (lane >> 4) * 4;
    const int cbase = lane & 15;
    #pragma unroll
    for (int mf = 0; mf < 4; ++mf) {
        #pragma unroll
        for (int nf = 0; nf < 4; ++nf) {
            const int col = n0 + wn + nf * 16 + cbase;
            const float bcol = bias[col];
            #pragma unroll
            for (int r = 0; r < 4; ++r) {
                const int row = m0 + wm + mf * 16 + rbase + r;
                float v = acc[mf][nf][r] + bcol;
                const size_t idx = (size_t)row * N + col;
                if (MODE == 0) {
                    ((ushort_t*)Cout)[idx] = f2bf(v);
                } else if (MODE == 1) {
                    ((ushort_t*)Cout)[idx] = f2bf(fmaxf(v, 0.0f));
                } else {
                    ((float*)Cout)[idx] = res[idx] + RES_ * v;
                }
            }
        }
    }
}

// ---------------------------------------------------------------------------
// Flash attention v4 (causal) from packed qkv (bf16 [8192][3072]).
// - Triangle flattened: block bx handles q-tiles {15-bx, bx} -> uniform 34 iters
// - 128 q-rows per tile; 4 waves x 32 rows (2 q-groups of 16); swapped QK^T
// - Async-STAGE: next KV tile prefetched to regs during compute (T14)
// - exp2-domain softmax (log2e folded into Q scale), cvt_pk P pack, setprio
// out: bf16 [8192][1024]
// ---------------------------------------------------------------------------
__global__ __launch_bounds__(256) void fattn_kernel(
    const ushort_t* __restrict__ qkv, ushort_t* __restrict__ out)
{
    __shared__ __align__(16) ushort_t Ks[64 * 64];     // [key][d], chunk c^=key&7
    __shared__ __align__(16) ushort_t Vt[64 * 64];     // [d][key], chunk c^=(d&7)^((d>>3)&7)
    __shared__ __align__(16) ushort_t Ps[4][32 * 64];  // per-wave [q][key], 16B-chunk c16^=q&7

    const int tid  = threadIdx.x;
    const int lane = tid & 63;
    const int w    = tid >> 6;
    const int bh = blockIdx.y;
    const int b = bh >> 4, h = bh & 15;

    const int l15 = lane & 15;
    const int g   = lane >> 4;

    const size_t rs = 3 * D_;
    const ushort_t* Qg = qkv + (size_t)b * S_ * rs + h * HD_;
    const ushort_t* Kg = Qg + D_;

    // staging geometry (constant per thread)
    const int skey = tid >> 3;          // 0..31 (+32 on pass 1)
    const int sc   = tid & 7;           // 16B chunk within row

    #pragma unroll
    for (int half = 0; half < 2; ++half) {
        const int qt = half ? blockIdx.x : (S_ / 128 - 1) - blockIdx.x;
        const int q0 = qt * 128;
        const int nkb = 2 * qt + 2;

        // Q B-frags (col=q=l15, k=g*8+e +kk*32), pre-scaled by SCALE_*log2e
        bf16x8 qf[2][2];
        #pragma unroll
        for (int qg = 0; qg < 2; ++qg) {
            const int qrow = q0 + w * 32 + qg * 16 + l15;
            #pragma unroll
            for (int kk = 0; kk < 2; ++kk) {
                bf16x8 t = *(const bf16x8*)(Qg + (size_t)qrow * rs + kk * 32 + g * 8);
                #pragma unroll
                for (int e = 0; e < 8; ++e)
                    t[e] = (short)f2bf(bf2f((ushort_t)t[e]) * (SCALE_ * LOG2E_));
                qf[qg][kk] = t;
            }
        }

        float mrow[2] = {-1e30f, -1e30f};
        float lrow[2] = {0.f, 0.f};
        f32x4 oacc[2][4] = {};   // [qg][d-frag]; D: col=d=l15, row(q-local)=g*4+r

        // prologue: load KV tile 0 into regs
        bf16x8 kvreg[2], vvreg[2];
        #pragma unroll
        for (int pass = 0; pass < 2; ++pass) {
            const ushort_t* src = Kg + (size_t)(pass * 32 + skey) * rs + sc * 8;
            kvreg[pass] = *(const bf16x8*)src;
            vvreg[pass] = *(const bf16x8*)(src + D_);
        }

        for (int kb = 0; kb < nkb; ++kb) {
            __syncthreads();   // prior compute done reading LDS
            // ---- write staged regs -> LDS (K swizzled b128, V^T scatter) ----
            #pragma unroll
            for (int pass = 0; pass < 2; ++pass) {
                const int key = pass * 32 + skey;
                *(bf16x8*)&Ks[key * 64 + ((sc ^ (key & 7)) << 3)] = kvreg[pass];
                #pragma unroll
                for (int j = 0; j < 8; ++j) {
                    const int d  = sc * 8 + j;
                    const int cp = (key >> 3) ^ (d & 7) ^ ((d >> 3) & 7);
                    Vt[d * 64 + (cp << 3) + (key & 7)] = (ushort_t)vvreg[pass][j];
                }
            }
            // ---- prefetch next KV tile into regs (hidden under compute) ----
            if (kb + 1 < nkb) {
                #pragma unroll
                for (int pass = 0; pass < 2; ++pass) {
                    const ushort_t* src =
                        Kg + (size_t)((kb + 1) * 64 + pass * 32 + skey) * rs + sc * 8;
                    kvreg[pass] = *(const bf16x8*)src;
                    vvreg[pass] = *(const bf16x8*)(src + D_);
                }
            }
            __syncthreads();   // staging visible

            // ---- S^T = K Q^T (D[key][q]: col=q=l15, row=key=g*4+r) ----
            f32x4 sf[2][4] = {};
            __builtin_amdgcn_s_setprio(1);
            #pragma unroll
            for (int kk = 0; kk < 2; ++kk) {
                const int cc = kk * 4 + g;
                #pragma unroll
                for (int nf = 0; nf < 4; ++nf) {
                    const int keyr = nf * 16 + l15;
                    bf16x8 kf = *(const bf16x8*)&Ks[keyr * 64 + ((cc ^ (keyr & 7)) << 3)];
                    sf[0][nf] = __builtin_amdgcn_mfma_f32_16x16x32_bf16(kf, qf[0][kk], sf[0][nf], 0, 0, 0);
                    sf[1][nf] = __builtin_amdgcn_mfma_f32_16x16x32_bf16(kf, qf[1][kk], sf[1][nf], 0, 0, 0);
                }
            }
            __builtin_amdgcn_s_setprio(0);

            // ---- mask + per-row max (lane owns q-row q0+w*32+qg*16+l15) ----
            float pm[2];
            #pragma unroll
            for (int qg = 0; qg < 2; ++qg) {
                const int qbase = q0 + w * 32 + qg * 16;
                if (kb * 64 + 63 > qbase) {           // wave-uniform guard
                    const int q = qbase + l15;
                    #pragma unroll
                    for (int nf = 0; nf < 4; ++nf)
                        #pragma unroll
                        for (int r = 0; r < 4; ++r)
                            if (kb * 64 + nf * 16 + g * 4 + r > q) sf[qg][nf][r] = -1e30f;
                }
                float mx = -1e30f;
                #pragma unroll
                for (int nf = 0; nf < 4; ++nf)
                    #pragma unroll
                    for (int r = 0; r < 4; ++r) mx = fmaxf(mx, sf[qg][nf][r]);
                mx = fmaxf(mx, __shfl_xor(mx, 16));
                mx = fmaxf(mx, __shfl_xor(mx, 32));
                pm[qg] = mx;
            }

            // ---- deferred-max rescale (T13, THR=8 in log2 units) ----
            const int ok = ((pm[0] - mrow[0]) <= 8.0f) & ((pm[1] - mrow[1]) <= 8.0f);
            if (!__all(ok)) {
                #pragma unroll
                for (int qg = 0; qg < 2; ++qg) {
                    const float mnew = fmaxf(mrow[qg], pm[qg]);
                    const float corr = fexp2(mrow[qg] - mnew);
                    mrow[qg] = mnew;
                    lrow[qg] *= corr;
                    #pragma unroll
                    for (int r = 0; r < 4; ++r) {
                        const float cr = __shfl(corr, g * 4 + r, 16);
                        #pragma unroll
                        for (int nf = 0; nf < 4; ++nf) oacc[qg][nf][r] *= cr;
                    }
                }
            }

            // ---- P = exp2(S - m), row-sum, packed write to Ps ----
            #pragma unroll
            for (int qg = 0; qg < 2; ++qg) {
                const int qrow = qg * 16 + l15;       // local row 0..31
                float psum = 0.f;
                #pragma unroll
                for (int nf = 0; nf < 4; ++nf) {
                    const float p0 = fexp2(sf[qg][nf][0] - mrow[qg]);
                    const float p1 = fexp2(sf[qg][nf][1] - mrow[qg]);
                    const float p2 = fexp2(sf[qg][nf][2] - mrow[qg]);
                    const float p3 = fexp2(sf[qg][nf][3] - mrow[qg]);
                    psum += (p0 + p1) + (p2 + p3);
                    uint2 pk = make_uint2(cvt_pk_bf16(p0, p1), cvt_pk_bf16(p2, p3));
                    const int c16 = ((nf << 1) + (g >> 1)) ^ (qrow & 7);
                    *(uint2*)((char*)Ps[w] + qrow * 128 + c16 * 16 + (g & 1) * 8) = pk;
                }
                psum += __shfl_xor(psum, 16);
                psum += __shfl_xor(psum, 32);
                lrow[qg] += psum;
            }

            // ---- O += P V (A=P from Ps, B=V^T from Vt) ----
            #pragma unroll
            for (int kk = 0; kk < 2; ++kk) {
                const int cc = kk * 4 + g;
                bf16x8 pa[2];
                #pragma unroll
                for (int qg = 0; qg < 2; ++qg) {
                    const int qrow = qg * 16 + l15;
                    const int c16 = (kk * 4 + g) ^ (qrow & 7);
                    pa[qg] = *(const bf16x8*)((const char*)Ps[w] + qrow * 128 + c16 * 16);
                }
                __builtin_amdgcn_s_setprio(1);
                #pragma unroll
                for (int nf = 0; nf < 4; ++nf) {
                    const int dr  = nf * 16 + l15;
                    const int cvp = cc ^ (dr & 7) ^ ((dr >> 3) & 7);
                    bf16x8 vf = *(const bf16x8*)&Vt[dr * 64 + (cvp << 3)];
                    oacc[0][nf] = __builtin_amdgcn_mfma_f32_16x16x32_bf16(pa[0], vf, oacc[0][nf], 0, 0, 0);
                    oacc[1][nf] = __builtin_amdgcn_mfma_f32_16x16x32_bf16(pa[1], vf, oacc[1][nf], 0, 0, 0);
                }
                __builtin_amdgcn_s_setprio(0);
            }
        }

        // ---- epilogue: O = acc / l (l lives at lane l15=row; broadcast via shfl) ----
        #pragma unroll
        for (int qg = 0; qg < 2; ++qg) {
            const float linv = 1.0f / lrow[qg];
            #pragma unroll
            for (int r = 0; r < 4; ++r) {
                const float li = __shfl(linv, g * 4 + r, 16);
                const int q = q0 + w * 32 + qg * 16 + g * 4 + r;
                ushort_t* op = out + (size_t)(b * S_ + q) * D_ + h * HD_;
                #pragma unroll
                for (int nf = 0; nf < 4; ++nf)
                    op[nf * 16 + l15] = f2bf(oacc[qg][nf][r] * li);
            }
        }
    }
}

// ---------------------------------------------------------------------------
// launch
// ---------------------------------------------------------------------------
extern "C" void kernel_launch(void* const* d_in, const int* in_sizes, int n_in,
                              void* d_out, int out_size, void* d_ws, size_t ws_size,
                              hipStream_t stream)
{
    const float* x   = (const float*)d_in[0];
    const float* Wq  = (const float*)d_in[1];
    const float* bq  = (const float*)d_in[2];
    const float* Wk  = (const float*)d_in[3];
    const float* bk  = (const float*)d_in[4];
    const float* Wv  = (const float*)d_in[5];
    const float* bv  = (const float*)d_in[6];
    const float* Wo  = (const float*)d_in[7];
    const float* bo  = (const float*)d_in[8];
    const float* g1  = (const float*)d_in[9];
    const float* be1 = (const float*)d_in[10];
    const float* g2  = (const float*)d_in[11];
    const float* be2 = (const float*)d_in[12];
    const float* W1  = (const float*)d_in[13];
    const float* b1  = (const float*)d_in[14];
    const float* W2  = (const float*)d_in[15];
    const float* b2  = (const float*)d_in[16];
    float* out = (float*)d_out;

    char* ws = (char*)d_ws;
    size_t o = 0;
    auto alloc = [&](size_t bytes) { size_t r = o; o = (o + bytes + 255) & ~(size_t)255; return r; };
    ushort_t* Wqkvt = (ushort_t*)(ws + alloc((size_t)3 * D_ * D_ * 2));   // [3072][1024]
    ushort_t* Wot   = (ushort_t*)(ws + alloc((size_t)D_ * D_ * 2));      // [1024][1024]
    ushort_t* W1t   = (ushort_t*)(ws + alloc((size_t)DFF_ * D_ * 2));    // [4096][1024]
    ushort_t* W2t   = (ushort_t*)(ws + alloc((size_t)D_ * DFF_ * 2));    // [1024][4096]
    float*    bqkv  = (float*)(ws + alloc((size_t)3 * D_ * 4));
    ushort_t* lnbuf = (ushort_t*)(ws + alloc((size_t)M_ * D_ * 2));      // ln1 then ln2
    ushort_t* bigbuf= (ushort_t*)(ws + alloc((size_t)M_ * DFF_ * 2));    // qkv then ffn-hidden
    ushort_t* attnb = (ushort_t*)(ws + alloc((size_t)M_ * D_ * 2));
    float*    x1    = (float*)(ws + alloc((size_t)M_ * D_ * 4));

    dim3 tblock(32, 8);
    transpose_cast_kernel<<<dim3(D_/32, D_/32), tblock, 0, stream>>>(Wq, Wqkvt,            D_, D_);
    transpose_cast_kernel<<<dim3(D_/32, D_/32), tblock, 0, stream>>>(Wk, Wqkvt + D_*D_,    D_, D_);
    transpose_cast_kernel<<<dim3(D_/32, D_/32), tblock, 0, stream>>>(Wv, Wqkvt + 2*D_*D_,  D_, D_);
    transpose_cast_kernel<<<dim3(D_/32, D_/32), tblock, 0, stream>>>(Wo, Wot,              D_, D_);
    transpose_cast_kernel<<<dim3(DFF_/32, D_/32), tblock, 0, stream>>>(W1, W1t,            D_, DFF_);
    transpose_cast_kernel<<<dim3(D_/32, DFF_/32), tblock, 0, stream>>>(W2, W2t,            DFF_, D_);
    concat_bias_kernel<<<12, 256, 0, stream>>>(bq, bk, bv, bqkv);

    // ln1
    ln_kernel<<<M_, 256, 0, stream>>>(x, g1, be1, lnbuf);
    // qkv = ln1 @ Wqkv + bqkv          [8192][3072] bf16
    gemm_bt_kernel<0><<<dim3(3*D_/128, M_/128), 256, 0, stream>>>(
        lnbuf, Wqkvt, bqkv, nullptr, bigbuf, M_, 3*D_, D_);
    // flash attention (paired q-tiles)  [8192][1024] bf16
    fattn_kernel<<<dim3(S_/256, B_*H_), 256, 0, stream>>>(bigbuf, attnb);
    // x1 = x + RES*(attn @ Wo + bo)     [8192][1024] fp32
    gemm_bt_kernel<2><<<dim3(D_/128, M_/128), 256, 0, stream>>>(
        attnb, Wot, bo, x, x1, M_, D_, D_);
    // ln2
    ln_kernel<<<M_, 256, 0, stream>>>(x1, g2, be2, lnbuf);
    // ffh = relu(ln2 @ W1 + b1)         [8192][4096] bf16
    gemm_bt_kernel<1><<<dim3(DFF_/128, M_/128), 256, 0, stream>>>(
        lnbuf, W1t, b1, nullptr, bigbuf, M_, DFF_, D_);
    // out = x1 + RES*(ffh @ W2 + b2)    [8192][1024] fp32
    gemm_bt_kernel<2><<<dim3(D_/128, M_/128), 256, 0, stream>>>(
        bigbuf, W2t, b2, x1, out, M_, D_, DFF_);
}

// Round 5
// 416.432 us; speedup vs baseline: 22.6246x; 1.1292x over previous
//
#include <hip/hip_runtime.h>

typedef unsigned short ushort_t;
typedef unsigned int uint32;
typedef __attribute__((ext_vector_type(4))) float f32x4;
typedef __attribute__((ext_vector_type(8))) short bf16x8;

#define B_   4
#define S_   2048
#define D_   1024
#define H_   16
#define HD_  64
#define DFF_ 4096
#define M_   (B_ * S_)          // 8192 rows (tokens)

#define RES_   0.28867513459481287f   // 1/sqrt(12)
#define SCALE_ 0.03125f               // 1/sqrt(1024)
#define EPS_   1e-5f
#define LOG2E_ 1.4426950408889634f

__device__ __forceinline__ ushort_t f2bf(float f) {
    union { float f; uint32 u; } c; c.f = f;
    uint32 u = c.u + 0x7fffu + ((c.u >> 16) & 1u);
    return (ushort_t)(u >> 16);
}
__device__ __forceinline__ float bf2f(ushort_t h) {
    union { uint32 u; float f; } c; c.u = ((uint32)h) << 16;
    return c.f;
}
__device__ __forceinline__ float fexp2(float x) {
    float r; asm("v_exp_f32 %0, %1" : "=v"(r) : "v"(x)); return r;
}
__device__ __forceinline__ uint32 cvt_pk_bf16(float lo, float hi) {
    uint32 r;
    asm("v_cvt_pk_bf16_f32 %0, %1, %2" : "=v"(r) : "v"(lo), "v"(hi));
    return r;
}

// ---------------------------------------------------------------------------
// Transpose + fp32->bf16 cast:  W[K][N] (fp32, row-major) -> Wt[N][K] (bf16)
// ---------------------------------------------------------------------------
__global__ __launch_bounds__(256) void transpose_cast_kernel(
    const float* __restrict__ W, ushort_t* __restrict__ Wt, int K, int N)
{
    __shared__ float tile[32][33];
    const int bx = blockIdx.x * 32;  // N offset
    const int by = blockIdx.y * 32;  // K offset
    const int tx = threadIdx.x;      // 0..31
    const int ty = threadIdx.y;      // 0..7
    #pragma unroll
    for (int i = 0; i < 32; i += 8)
        tile[ty + i][tx] = W[(size_t)(by + ty + i) * N + bx + tx];
    __syncthreads();
    #pragma unroll
    for (int i = 0; i < 32; i += 8)
        Wt[(size_t)(bx + ty + i) * K + by + tx] = f2bf(tile[tx][ty + i]);
}

// ---------------------------------------------------------------------------
// Concat bq,bk,bv -> bqkv[3072]
// ---------------------------------------------------------------------------
__global__ void concat_bias_kernel(const float* __restrict__ bq,
                                   const float* __restrict__ bk,
                                   const float* __restrict__ bv,
                                   float* __restrict__ bqkv)
{
    int i = blockIdx.x * blockDim.x + threadIdx.x;
    if (i < 3 * D_) {
        float v = (i < D_) ? bq[i] : (i < 2 * D_) ? bk[i - D_] : bv[i - 2 * D_];
        bqkv[i] = v;
    }
}

// ---------------------------------------------------------------------------
// LayerNorm: fp32 in [rows][1024] -> bf16 out
// ---------------------------------------------------------------------------
__global__ __launch_bounds__(256) void ln_kernel(
    const float* __restrict__ x, const float* __restrict__ g,
    const float* __restrict__ be, ushort_t* __restrict__ out)
{
    const int row = blockIdx.x;
    const int t = threadIdx.x;
    const int lane = t & 63;
    const int wave = t >> 6;
    const float4* xr = (const float4*)(x + (size_t)row * D_);
    float4 v = xr[t];
    float s  = v.x + v.y + v.z + v.w;
    float s2 = v.x * v.x + v.y * v.y + v.z * v.z + v.w * v.w;
    #pragma unroll
    for (int off = 32; off; off >>= 1) {
        s  += __shfl_xor(s, off);
        s2 += __shfl_xor(s2, off);
    }
    __shared__ float red[8];
    if (lane == 0) { red[wave * 2] = s; red[wave * 2 + 1] = s2; }
    __syncthreads();
    s  = red[0] + red[2] + red[4] + red[6];
    s2 = red[1] + red[3] + red[5] + red[7];
    const float mean = s * (1.0f / D_);
    const float var  = s2 * (1.0f / D_) - mean * mean;
    const float rstd = rsqrtf(var + EPS_);
    const float4 gv  = ((const float4*)g)[t];
    const float4 bv  = ((const float4*)be)[t];
    ushort_t o[4];
    o[0] = f2bf((v.x - mean) * rstd * gv.x + bv.x);
    o[1] = f2bf((v.y - mean) * rstd * gv.y + bv.y);
    o[2] = f2bf((v.z - mean) * rstd * gv.z + bv.z);
    o[3] = f2bf((v.w - mean) * rstd * gv.w + bv.w);
    *(ushort2*)&out[(size_t)row * D_ + t * 4]     = make_ushort2(o[0], o[1]);
    *(ushort2*)&out[(size_t)row * D_ + t * 4 + 2] = make_ushort2(o[2], o[3]);
}

// ---------------------------------------------------------------------------
// GEMM v2: C[M][N] = epilogue(A[M][K] @ Bt[N][K]^T + bias)
// BM=256, BN=128, BK=32, 8 waves (512 thr), double-buffered LDS (48KB),
// T2 swizzle (linear LDS dest + inverse-swizzled global src + swizzled reads),
// T1 bijective XCD swizzle (grid %8==0), T5 setprio.
// Wave layout: 4M x 2N, per-wave 64x64 (4x4 16x16x32 frags).
// ---------------------------------------------------------------------------
template <int MODE>
__global__ __launch_bounds__(512, 2) void gemm_bt2_kernel(
    const ushort_t* __restrict__ A, const ushort_t* __restrict__ Bt,
    const float* __restrict__ bias, const float* __restrict__ res,
    void* __restrict__ Cout, int M, int N, int K, int gx)
{
    // [buf][row][4 chunks of 16B]; stored chunk = logical ^ (row&3)
    __shared__ __align__(16) ushort_t As[2][256 * 32];
    __shared__ __align__(16) ushort_t Bs[2][128 * 32];

    const int tid  = threadIdx.x;
    const int w    = tid >> 6;
    const int lane = tid & 63;
    const int l15  = lane & 15;
    const int g    = lane >> 4;

    // T1: bijective XCD swizzle (gridDim.x % 8 == 0)
    const int cpx = gridDim.x >> 3;
    const int swz = (blockIdx.x & 7) * cpx + (blockIdx.x >> 3);
    const int bx = swz % gx, by = swz / gx;
    const int m0 = by * 256, n0 = bx * 128;

    const int wm = (w >> 1) * 64;   // 0,64,128,192
    const int wn = (w & 1) * 64;    // 0,64

    // staging geometry: A has 1024 16B-chunks (2 passes), B has 512 (1 pass)
    // chunk L -> row = L>>2, stored c = L&3, logical c = (L&3)^(row&3)
    const int La0 = w * 64 + lane;          // A pass 0
    const int La1 = 512 + La0;              // A pass 1
    const int Lb  = w * 64 + lane;          // B pass 0
    const int rowA0 = La0 >> 2, cA0 = (La0 & 3) ^ (rowA0 & 3);
    const int rowA1 = La1 >> 2, cA1 = (La1 & 3) ^ (rowA1 & 3);
    const int rowB  = Lb  >> 2, cB  = (Lb  & 3) ^ (rowB  & 3);
    const ushort_t* srcA0 = A  + (size_t)(m0 + rowA0) * K + cA0 * 8;
    const ushort_t* srcA1 = A  + (size_t)(m0 + rowA1) * K + cA1 * 8;
    const ushort_t* srcB  = Bt + (size_t)(n0 + rowB)  * K + cB  * 8;
    // wave-uniform LDS bases (HW adds lane*16)
    const int ldsA0 = (w * 64) * 8;
    const int ldsA1 = (512 + w * 64) * 8;
    const int ldsB  = (w * 64) * 8;

    #define STAGE(t_, p_)                                                         \
        do {                                                                      \
            __builtin_amdgcn_global_load_lds(                                     \
                (const __attribute__((address_space(1))) void*)(srcA0 + (t_) * 32), \
                (__attribute__((address_space(3))) void*)(&As[p_][ldsA0]), 16, 0, 0); \
            __builtin_amdgcn_global_load_lds(                                     \
                (const __attribute__((address_space(1))) void*)(srcA1 + (t_) * 32), \
                (__attribute__((address_space(3))) void*)(&As[p_][ldsA1]), 16, 0, 0); \
            __builtin_amdgcn_global_load_lds(                                     \
                (const __attribute__((address_space(1))) void*)(srcB + (t_) * 32),  \
                (__attribute__((address_space(3))) void*)(&Bs[p_][ldsB]), 16, 0, 0);  \
        } while (0)

    f32x4 acc[4][4] = {};
    const int NT = K >> 5;

    STAGE(0, 0);
    __syncthreads();

    for (int t = 0; t < NT; ++t) {
        const int cur = t & 1;
        if (t + 1 < NT) STAGE(t + 1, cur ^ 1);

        bf16x8 af[4], bfr[4];
        #pragma unroll
        for (int mf = 0; mf < 4; ++mf) {
            const int row = wm + mf * 16 + l15;
            const int cs  = g ^ (row & 3);
            af[mf] = *(const bf16x8*)&As[cur][row * 32 + cs * 8];
        }
        #pragma unroll
        for (int nf = 0; nf < 4; ++nf) {
            const int row = wn + nf * 16 + l15;
            const int cs  = g ^ (row & 3);
            bfr[nf] = *(const bf16x8*)&Bs[cur][row * 32 + cs * 8];
        }
        __builtin_amdgcn_s_setprio(1);
        #pragma unroll
        for (int mf = 0; mf < 4; ++mf)
            #pragma unroll
            for (int nf = 0; nf < 4; ++nf)
                acc[mf][nf] = __builtin_amdgcn_mfma_f32_16x16x32_bf16(
                    af[mf], bfr[nf], acc[mf][nf], 0, 0, 0);
        __builtin_amdgcn_s_setprio(0);
        __syncthreads();
    }
    #undef STAGE

    // epilogue: C/D layout col = lane&15, row = (lane>>4)*4 + r
    const int rbase = g * 4;
    #pragma unroll
    for (int mf = 0; mf < 4; ++mf) {
        #pragma unroll
        for (int nf = 0; nf < 4; ++nf) {
            const int col = n0 + wn + nf * 16 + l15;
            const float bcol = bias[col];
            #pragma unroll
            for (int r = 0; r < 4; ++r) {
                const int row = m0 + wm + mf * 16 + rbase + r;
                float v = acc[mf][nf][r] + bcol;
                const size_t idx = (size_t)row * N + col;
                if (MODE == 0) {
                    ((ushort_t*)Cout)[idx] = f2bf(v);
                } else if (MODE == 1) {
                    ((ushort_t*)Cout)[idx] = f2bf(fmaxf(v, 0.0f));
                } else {
                    ((float*)Cout)[idx] = res[idx] + RES_ * v;
                }
            }
        }
    }
}

// ---------------------------------------------------------------------------
// Flash attention v5 (causal) from packed qkv (bf16 [8192][3072]).
// - 64-row q-tiles, 4 waves x 16 rows -> 4096 waves total (2x parallelism)
// - paired triangle: block bx does q-tiles {31-bx, bx} -> uniform 33 iters
// - swapped QK^T, reg-prefetch staging (T14), exp2 softmax, defer-max (T13)
// out: bf16 [8192][1024]
// ---------------------------------------------------------------------------
__global__ __launch_bounds__(256) void fattn_kernel(
    const ushort_t* __restrict__ qkv, ushort_t* __restrict__ out)
{
    __shared__ __align__(16) ushort_t Ks[64 * 64];     // [key][d], chunk c^=key&7
    __shared__ __align__(16) ushort_t Vt[64 * 64];     // [d][key], chunk c^=(d&7)^((d>>3)&7)
    __shared__ __align__(16) ushort_t Ps[4][16 * 64];  // per-wave [q][key], 16B-chunk c16^=q&7

    const int tid  = threadIdx.x;
    const int lane = tid & 63;
    const int w    = tid >> 6;
    const int bh = blockIdx.y;
    const int b = bh >> 4, h = bh & 15;

    const int l15 = lane & 15;
    const int g   = lane >> 4;

    const size_t rs = 3 * D_;
    const ushort_t* Qg = qkv + (size_t)b * S_ * rs + h * HD_;
    const ushort_t* Kg = Qg + D_;

    // staging geometry (constant per thread)
    const int skey = tid >> 3;          // 0..31 (+32 on pass 1)
    const int sc   = tid & 7;           // 16B chunk within row

    #pragma unroll
    for (int half = 0; half < 2; ++half) {
        const int qt = half ? blockIdx.x : (S_ / 64 - 1) - blockIdx.x;
        const int q0 = qt * 64;
        const int nkb = qt + 1;

        // Q B-frags (col=q=l15, k=g*8+e +kk*32), pre-scaled by SCALE_*log2e
        bf16x8 qf[2];
        {
            const int qrow = q0 + w * 16 + l15;
            #pragma unroll
            for (int kk = 0; kk < 2; ++kk) {
                bf16x8 tq = *(const bf16x8*)(Qg + (size_t)qrow * rs + kk * 32 + g * 8);
                #pragma unroll
                for (int e = 0; e < 8; ++e)
                    tq[e] = (short)f2bf(bf2f((ushort_t)tq[e]) * (SCALE_ * LOG2E_));
                qf[kk] = tq;
            }
        }

        float mrow = -1e30f, lrow = 0.f;
        f32x4 oacc[4] = {};   // d-frags; D: col=d=l15, row(q-local)=g*4+r

        // prologue: load KV tile 0 into regs
        bf16x8 kvreg[2], vvreg[2];
        #pragma unroll
        for (int pass = 0; pass < 2; ++pass) {
            const ushort_t* src = Kg + (size_t)(pass * 32 + skey) * rs + sc * 8;
            kvreg[pass] = *(const bf16x8*)src;
            vvreg[pass] = *(const bf16x8*)(src + D_);
        }

        for (int kb = 0; kb < nkb; ++kb) {
            __syncthreads();   // prior compute done reading LDS
            // ---- write staged regs -> LDS (K swizzled b128, V^T scatter) ----
            #pragma unroll
            for (int pass = 0; pass < 2; ++pass) {
                const int key = pass * 32 + skey;
                *(bf16x8*)&Ks[key * 64 + ((sc ^ (key & 7)) << 3)] = kvreg[pass];
                #pragma unroll
                for (int j = 0; j < 8; ++j) {
                    const int d  = sc * 8 + j;
                    const int cp = (key >> 3) ^ (d & 7) ^ ((d >> 3) & 7);
                    Vt[d * 64 + (cp << 3) + (key & 7)] = (ushort_t)vvreg[pass][j];
                }
            }
            // ---- prefetch next KV tile into regs (hidden under compute) ----
            if (kb + 1 < nkb) {
                #pragma unroll
                for (int pass = 0; pass < 2; ++pass) {
                    const ushort_t* src =
                        Kg + (size_t)((kb + 1) * 64 + pass * 32 + skey) * rs + sc * 8;
                    kvreg[pass] = *(const bf16x8*)src;
                    vvreg[pass] = *(const bf16x8*)(src + D_);
                }
            }
            __syncthreads();   // staging visible

            // ---- S^T = K Q^T (D[key][q]: col=q=l15, row=key=g*4+r) ----
            f32x4 sf[4] = {};
            __builtin_amdgcn_s_setprio(1);
            #pragma unroll
            for (int kk = 0; kk < 2; ++kk) {
                const int cc = kk * 4 + g;
                #pragma unroll
                for (int nf = 0; nf < 4; ++nf) {
                    const int keyr = nf * 16 + l15;
                    bf16x8 kf = *(const bf16x8*)&Ks[keyr * 64 + ((cc ^ (keyr & 7)) << 3)];
                    sf[nf] = __builtin_amdgcn_mfma_f32_16x16x32_bf16(kf, qf[kk], sf[nf], 0, 0, 0);
                }
            }
            __builtin_amdgcn_s_setprio(0);

            // ---- mask (only last kv-block can cross the diagonal) ----
            if (kb == nkb - 1) {
                const int q = q0 + w * 16 + l15;
                #pragma unroll
                for (int nf = 0; nf < 4; ++nf)
                    #pragma unroll
                    for (int r = 0; r < 4; ++r)
                        if (kb * 64 + nf * 16 + g * 4 + r > q) sf[nf][r] = -1e30f;
            }
            // ---- per-row max ----
            float mx = -1e30f;
            #pragma unroll
            for (int nf = 0; nf < 4; ++nf)
                #pragma unroll
                for (int r = 0; r < 4; ++r) mx = fmaxf(mx, sf[nf][r]);
            mx = fmaxf(mx, __shfl_xor(mx, 16));
            mx = fmaxf(mx, __shfl_xor(mx, 32));

            // ---- deferred-max rescale (T13, THR=8 in log2 units) ----
            if (!__all(mx - mrow <= 8.0f)) {
                const float mnew = fmaxf(mrow, mx);
                const float corr = fexp2(mrow - mnew);
                mrow = mnew;
                lrow *= corr;
                #pragma unroll
                for (int r = 0; r < 4; ++r) {
                    const float cr = __shfl(corr, g * 4 + r, 16);
                    #pragma unroll
                    for (int nf = 0; nf < 4; ++nf) oacc[nf][r] *= cr;
                }
            }

            // ---- P = exp2(S - m), row-sum, packed write to Ps ----
            {
                const int qrow = l15;
                float psum = 0.f;
                #pragma unroll
                for (int nf = 0; nf < 4; ++nf) {
                    const float p0 = fexp2(sf[nf][0] - mrow);
                    const float p1 = fexp2(sf[nf][1] - mrow);
                    const float p2 = fexp2(sf[nf][2] - mrow);
                    const float p3 = fexp2(sf[nf][3] - mrow);
                    psum += (p0 + p1) + (p2 + p3);
                    uint2 pk = make_uint2(cvt_pk_bf16(p0, p1), cvt_pk_bf16(p2, p3));
                    const int c16 = ((nf << 1) + (g >> 1)) ^ (qrow & 7);
                    *(uint2*)((char*)Ps[w] + qrow * 128 + c16 * 16 + (g & 1) * 8) = pk;
                }
                psum += __shfl_xor(psum, 16);
                psum += __shfl_xor(psum, 32);
                lrow += psum;
            }

            // ---- O += P V (A=P from Ps, B=V^T from Vt) ----
            #pragma unroll
            for (int kk = 0; kk < 2; ++kk) {
                const int cc = kk * 4 + g;
                const int qrow = l15;
                const int c16 = cc ^ (qrow & 7);
                bf16x8 pa = *(const bf16x8*)((const char*)Ps[w] + qrow * 128 + c16 * 16);
                __builtin_amdgcn_s_setprio(1);
                #pragma unroll
                for (int nf = 0; nf < 4; ++nf) {
                    const int dr  = nf * 16 + l15;
                    const int cvp = cc ^ (dr & 7) ^ ((dr >> 3) & 7);
                    bf16x8 vf = *(const bf16x8*)&Vt[dr * 64 + (cvp << 3)];
                    oacc[nf] = __builtin_amdgcn_mfma_f32_16x16x32_bf16(pa, vf, oacc[nf], 0, 0, 0);
                }
                __builtin_amdgcn_s_setprio(0);
            }
        }

        // ---- epilogue: O = acc / l (l lives at lane l15=row; broadcast) ----
        const float linv = 1.0f / lrow;
        #pragma unroll
        for (int r = 0; r < 4; ++r) {
            const float li = __shfl(linv, g * 4 + r, 16);
            const int q = q0 + w * 16 + g * 4 + r;
            ushort_t* op = out + (size_t)(b * S_ + q) * D_ + h * HD_;
            #pragma unroll
            for (int nf = 0; nf < 4; ++nf)
                op[nf * 16 + l15] = f2bf(oacc[nf][r] * li);
        }
    }
}

// ---------------------------------------------------------------------------
// launch
// ---------------------------------------------------------------------------
extern "C" void kernel_launch(void* const* d_in, const int* in_sizes, int n_in,
                              void* d_out, int out_size, void* d_ws, size_t ws_size,
                              hipStream_t stream)
{
    const float* x   = (const float*)d_in[0];
    const float* Wq  = (const float*)d_in[1];
    const float* bq  = (const float*)d_in[2];
    const float* Wk  = (const float*)d_in[3];
    const float* bk  = (const float*)d_in[4];
    const float* Wv  = (const float*)d_in[5];
    const float* bv  = (const float*)d_in[6];
    const float* Wo  = (const float*)d_in[7];
    const float* bo  = (const float*)d_in[8];
    const float* g1  = (const float*)d_in[9];
    const float* be1 = (const float*)d_in[10];
    const float* g2  = (const float*)d_in[11];
    const float* be2 = (const float*)d_in[12];
    const float* W1  = (const float*)d_in[13];
    const float* b1  = (const float*)d_in[14];
    const float* W2  = (const float*)d_in[15];
    const float* b2  = (const float*)d_in[16];
    float* out = (float*)d_out;

    char* ws = (char*)d_ws;
    size_t o = 0;
    auto alloc = [&](size_t bytes) { size_t r = o; o = (o + bytes + 255) & ~(size_t)255; return r; };
    ushort_t* Wqkvt = (ushort_t*)(ws + alloc((size_t)3 * D_ * D_ * 2));   // [3072][1024]
    ushort_t* Wot   = (ushort_t*)(ws + alloc((size_t)D_ * D_ * 2));      // [1024][1024]
    ushort_t* W1t   = (ushort_t*)(ws + alloc((size_t)DFF_ * D_ * 2));    // [4096][1024]
    ushort_t* W2t   = (ushort_t*)(ws + alloc((size_t)D_ * DFF_ * 2));    // [1024][4096]
    float*    bqkv  = (float*)(ws + alloc((size_t)3 * D_ * 4));
    ushort_t* lnbuf = (ushort_t*)(ws + alloc((size_t)M_ * D_ * 2));      // ln1 then ln2
    ushort_t* bigbuf= (ushort_t*)(ws + alloc((size_t)M_ * DFF_ * 2));    // qkv then ffn-hidden
    ushort_t* attnb = (ushort_t*)(ws + alloc((size_t)M_ * D_ * 2));
    float*    x1    = (float*)(ws + alloc((size_t)M_ * D_ * 4));

    dim3 tblock(32, 8);
    transpose_cast_kernel<<<dim3(D_/32, D_/32), tblock, 0, stream>>>(Wq, Wqkvt,            D_, D_);
    transpose_cast_kernel<<<dim3(D_/32, D_/32), tblock, 0, stream>>>(Wk, Wqkvt + D_*D_,    D_, D_);
    transpose_cast_kernel<<<dim3(D_/32, D_/32), tblock, 0, stream>>>(Wv, Wqkvt + 2*D_*D_,  D_, D_);
    transpose_cast_kernel<<<dim3(D_/32, D_/32), tblock, 0, stream>>>(Wo, Wot,              D_, D_);
    transpose_cast_kernel<<<dim3(DFF_/32, D_/32), tblock, 0, stream>>>(W1, W1t,            D_, DFF_);
    transpose_cast_kernel<<<dim3(D_/32, DFF_/32), tblock, 0, stream>>>(W2, W2t,            DFF_, D_);
    concat_bias_kernel<<<12, 256, 0, stream>>>(bq, bk, bv, bqkv);

    // ln1
    ln_kernel<<<M_, 256, 0, stream>>>(x, g1, be1, lnbuf);
    // qkv = ln1 @ Wqkv + bqkv          [8192][3072] bf16   grid 32x24=768
    gemm_bt2_kernel<0><<<(M_/256)*(3*D_/128), 512, 0, stream>>>(
        lnbuf, Wqkvt, bqkv, nullptr, bigbuf, M_, 3*D_, D_, 3*D_/128);
    // flash attention (paired q-tiles)  [8192][1024] bf16
    fattn_kernel<<<dim3(S_/128, B_*H_), 256, 0, stream>>>(bigbuf, attnb);
    // x1 = x + RES*(attn @ Wo + bo)     [8192][1024] fp32  grid 32x8=256
    gemm_bt2_kernel<2><<<(M_/256)*(D_/128), 512, 0, stream>>>(
        attnb, Wot, bo, x, x1, M_, D_, D_, D_/128);
    // ln2
    ln_kernel<<<M_, 256, 0, stream>>>(x1, g2, be2, lnbuf);
    // ffh = relu(ln2 @ W1 + b1)         [8192][4096] bf16  grid 32x32=1024
    gemm_bt2_kernel<1><<<(M_/256)*(DFF_/128), 512, 0, stream>>>(
        lnbuf, W1t, b1, nullptr, bigbuf, M_, DFF_, D_, DFF_/128);
    // out = x1 + RES*(ffh @ W2 + b2)    [8192][1024] fp32  grid 32x8=256
    gemm_bt2_kernel<2><<<(M_/256)*(D_/128), 512, 0, stream>>>(
        bigbuf, W2t, b2, x1, out, M_, D_, DFF_, D_/128);
}

// Round 6
// 410.668 us; speedup vs baseline: 22.9421x; 1.0140x over previous
//
#include <hip/hip_runtime.h>

typedef unsigned short ushort_t;
typedef unsigned int uint32;
typedef __attribute__((ext_vector_type(4))) float f32x4;
typedef __attribute__((ext_vector_type(8))) short bf16x8;

#define B_   4
#define S_   2048
#define D_   1024
#define H_   16
#define HD_  64
#define DFF_ 4096
#define M_   (B_ * S_)          // 8192 rows (tokens)

#define RES_   0.28867513459481287f   // 1/sqrt(12)
#define SCALE_ 0.03125f               // 1/sqrt(1024)
#define EPS_   1e-5f
#define LOG2E_ 1.4426950408889634f

__device__ __forceinline__ ushort_t f2bf(float f) {
    union { float f; uint32 u; } c; c.f = f;
    uint32 u = c.u + 0x7fffu + ((c.u >> 16) & 1u);
    return (ushort_t)(u >> 16);
}
__device__ __forceinline__ float bf2f(ushort_t h) {
    union { uint32 u; float f; } c; c.u = ((uint32)h) << 16;
    return c.f;
}
__device__ __forceinline__ float fexp2(float x) {
    float r; asm("v_exp_f32 %0, %1" : "=v"(r) : "v"(x)); return r;
}
__device__ __forceinline__ uint32 cvt_pk_bf16(float lo, float hi) {
    uint32 r;
    asm("v_cvt_pk_bf16_f32 %0, %1, %2" : "=v"(r) : "v"(lo), "v"(hi));
    return r;
}

// ---------------------------------------------------------------------------
// Transpose + fp32->bf16 cast:  W[K][N] (fp32, row-major) -> Wt[N][K] (bf16)
// ---------------------------------------------------------------------------
__global__ __launch_bounds__(256) void transpose_cast_kernel(
    const float* __restrict__ W, ushort_t* __restrict__ Wt, int K, int N)
{
    __shared__ float tile[32][33];
    const int bx = blockIdx.x * 32;  // N offset
    const int by = blockIdx.y * 32;  // K offset
    const int tx = threadIdx.x;      // 0..31
    const int ty = threadIdx.y;      // 0..7
    #pragma unroll
    for (int i = 0; i < 32; i += 8)
        tile[ty + i][tx] = W[(size_t)(by + ty + i) * N + bx + tx];
    __syncthreads();
    #pragma unroll
    for (int i = 0; i < 32; i += 8)
        Wt[(size_t)(bx + ty + i) * K + by + tx] = f2bf(tile[tx][ty + i]);
}

// ---------------------------------------------------------------------------
// Concat bq,bk,bv -> bqkv[3072]
// ---------------------------------------------------------------------------
__global__ void concat_bias_kernel(const float* __restrict__ bq,
                                   const float* __restrict__ bk,
                                   const float* __restrict__ bv,
                                   float* __restrict__ bqkv)
{
    int i = blockIdx.x * blockDim.x + threadIdx.x;
    if (i < 3 * D_) {
        float v = (i < D_) ? bq[i] : (i < 2 * D_) ? bk[i - D_] : bv[i - 2 * D_];
        bqkv[i] = v;
    }
}

// ---------------------------------------------------------------------------
// LayerNorm: fp32 in [rows][1024] -> bf16 out
// ---------------------------------------------------------------------------
__global__ __launch_bounds__(256) void ln_kernel(
    const float* __restrict__ x, const float* __restrict__ g,
    const float* __restrict__ be, ushort_t* __restrict__ out)
{
    const int row = blockIdx.x;
    const int t = threadIdx.x;
    const int lane = t & 63;
    const int wave = t >> 6;
    const float4* xr = (const float4*)(x + (size_t)row * D_);
    float4 v = xr[t];
    float s  = v.x + v.y + v.z + v.w;
    float s2 = v.x * v.x + v.y * v.y + v.z * v.z + v.w * v.w;
    #pragma unroll
    for (int off = 32; off; off >>= 1) {
        s  += __shfl_xor(s, off);
        s2 += __shfl_xor(s2, off);
    }
    __shared__ float red[8];
    if (lane == 0) { red[wave * 2] = s; red[wave * 2 + 1] = s2; }
    __syncthreads();
    s  = red[0] + red[2] + red[4] + red[6];
    s2 = red[1] + red[3] + red[5] + red[7];
    const float mean = s * (1.0f / D_);
    const float var  = s2 * (1.0f / D_) - mean * mean;
    const float rstd = rsqrtf(var + EPS_);
    const float4 gv  = ((const float4*)g)[t];
    const float4 bv  = ((const float4*)be)[t];
    ushort_t o[4];
    o[0] = f2bf((v.x - mean) * rstd * gv.x + bv.x);
    o[1] = f2bf((v.y - mean) * rstd * gv.y + bv.y);
    o[2] = f2bf((v.z - mean) * rstd * gv.z + bv.z);
    o[3] = f2bf((v.w - mean) * rstd * gv.w + bv.w);
    *(ushort2*)&out[(size_t)row * D_ + t * 4]     = make_ushort2(o[0], o[1]);
    *(ushort2*)&out[(size_t)row * D_ + t * 4 + 2] = make_ushort2(o[2], o[3]);
}

// ---------------------------------------------------------------------------
// GEMM v3: C[M][N] = epilogue(A[M][K] @ Bt[N][K]^T + bias)
// BN=128, BK=32. BM=256 (8 waves) or BM=128 (4 waves).
// 3-deep LDS rotation, counted vmcnt (T4) + raw s_barrier: tile t+2's loads
// stay in flight across the barrier; only t+1's must land (issued a full
// iteration earlier). Linear LDS both sides (BK=32 frag reads are
// conflict-free: contiguous 1KiB per wave). T1 bijective XCD swizzle, T5.
// ---------------------------------------------------------------------------
template <int MODE, int BM>
__global__ __launch_bounds__((BM == 256) ? 512 : 256, (BM == 256) ? 2 : 3)
void gemm_bt3_kernel(
    const ushort_t* __restrict__ A, const ushort_t* __restrict__ Bt,
    const float* __restrict__ bias, const float* __restrict__ res,
    void* __restrict__ Cout, int M, int N, int K, int gx)
{
    constexpr int THREADS = (BM == 256) ? 512 : 256;
    constexpr int APASS = (BM * 4) / THREADS;      // 16B chunks per thread (A)
    constexpr int BPASS = (128 * 4) / THREADS;     // 16B chunks per thread (B)
    constexpr int LOADS = APASS + BPASS;           // gload_lds per STAGE

    __shared__ __align__(16) ushort_t As[3][BM * 32];
    __shared__ __align__(16) ushort_t Bs[3][128 * 32];

    const int tid  = threadIdx.x;
    const int w    = tid >> 6;
    const int lane = tid & 63;
    const int l15  = lane & 15;
    const int g    = lane >> 4;

    // T1: bijective XCD swizzle (gridDim.x % 8 == 0)
    const int cpx = gridDim.x >> 3;
    const int swz = (blockIdx.x & 7) * cpx + (blockIdx.x >> 3);
    const int bx = swz % gx, by = swz / gx;
    const int m0 = by * BM, n0 = bx * 128;

    const int wm = (w >> 1) * 64;
    const int wn = (w & 1) * 64;

    // staging geometry: chunk L -> row = L>>2, col-chunk = L&3 (linear)
    const ushort_t* srcA[APASS];
    const ushort_t* srcB[BPASS];
    int ldsA[APASS], ldsB[BPASS];
    #pragma unroll
    for (int p = 0; p < APASS; ++p) {
        const int L = p * THREADS + tid;
        srcA[p] = A + (size_t)(m0 + (L >> 2)) * K + (L & 3) * 8;
        ldsA[p] = (p * THREADS + w * 64) * 8;   // wave-uniform; HW adds lane*16B
    }
    #pragma unroll
    for (int p = 0; p < BPASS; ++p) {
        const int L = p * THREADS + tid;
        srcB[p] = Bt + (size_t)(n0 + (L >> 2)) * K + (L & 3) * 8;
        ldsB[p] = (p * THREADS + w * 64) * 8;
    }

    #define STAGE(t_, buf_)                                                        \
        do {                                                                       \
            _Pragma("unroll")                                                      \
            for (int p = 0; p < APASS; ++p)                                        \
                __builtin_amdgcn_global_load_lds(                                  \
                    (const __attribute__((address_space(1))) void*)(srcA[p] + (t_) * 32), \
                    (__attribute__((address_space(3))) void*)(&As[buf_][ldsA[p]]), 16, 0, 0); \
            _Pragma("unroll")                                                      \
            for (int p = 0; p < BPASS; ++p)                                        \
                __builtin_amdgcn_global_load_lds(                                  \
                    (const __attribute__((address_space(1))) void*)(srcB[p] + (t_) * 32), \
                    (__attribute__((address_space(3))) void*)(&Bs[buf_][ldsB[p]]), 16, 0, 0); \
        } while (0)

    f32x4 acc[4][4] = {};
    const int NT = K >> 5;

    STAGE(0, 0);
    STAGE(1, 1);
    asm volatile("s_waitcnt vmcnt(%0)" :: "n"(LOADS) : "memory");  // tile0 landed
    __builtin_amdgcn_s_barrier();

    for (int t = 0; t < NT; ++t) {
        const int cur = t % 3;
        const bool more = (t + 2 < NT);
        if (more) STAGE(t + 2, (t + 2) % 3);

        bf16x8 af[4], bfr[4];
        #pragma unroll
        for (int mf = 0; mf < 4; ++mf)
            af[mf] = *(const bf16x8*)&As[cur][(wm + mf * 16 + l15) * 32 + g * 8];
        #pragma unroll
        for (int nf = 0; nf < 4; ++nf)
            bfr[nf] = *(const bf16x8*)&Bs[cur][(wn + nf * 16 + l15) * 32 + g * 8];

        __builtin_amdgcn_s_setprio(1);
        #pragma unroll
        for (int mf = 0; mf < 4; ++mf)
            #pragma unroll
            for (int nf = 0; nf < 4; ++nf)
                acc[mf][nf] = __builtin_amdgcn_mfma_f32_16x16x32_bf16(
                    af[mf], bfr[nf], acc[mf][nf], 0, 0, 0);
        __builtin_amdgcn_s_setprio(0);

        if (more)
            asm volatile("s_waitcnt vmcnt(%0)" :: "n"(LOADS) : "memory");  // t+1 ready
        else
            asm volatile("s_waitcnt vmcnt(0)" ::: "memory");
        __builtin_amdgcn_s_barrier();
    }
    #undef STAGE

    // epilogue: C/D layout col = lane&15, row = (lane>>4)*4 + r
    const int rbase = g * 4;
    #pragma unroll
    for (int mf = 0; mf < 4; ++mf) {
        #pragma unroll
        for (int nf = 0; nf < 4; ++nf) {
            const int col = n0 + wn + nf * 16 + l15;
            const float bcol = bias[col];
            #pragma unroll
            for (int r = 0; r < 4; ++r) {
                const int row = m0 + wm + mf * 16 + rbase + r;
                float v = acc[mf][nf][r] + bcol;
                const size_t idx = (size_t)row * N + col;
                if (MODE == 0) {
                    ((ushort_t*)Cout)[idx] = f2bf(v);
                } else if (MODE == 1) {
                    ((ushort_t*)Cout)[idx] = f2bf(fmaxf(v, 0.0f));
                } else {
                    ((float*)Cout)[idx] = res[idx] + RES_ * v;
                }
            }
        }
    }
}

// ---------------------------------------------------------------------------
// Flash attention v5 (causal) from packed qkv (bf16 [8192][3072]).
// - 64-row q-tiles, 4 waves x 16 rows; paired triangle (uniform 33 iters)
// - swapped QK^T, reg-prefetch staging (T14), exp2 softmax, defer-max (T13)
// out: bf16 [8192][1024]
// ---------------------------------------------------------------------------
__global__ __launch_bounds__(256) void fattn_kernel(
    const ushort_t* __restrict__ qkv, ushort_t* __restrict__ out)
{
    __shared__ __align__(16) ushort_t Ks[64 * 64];     // [key][d], chunk c^=key&7
    __shared__ __align__(16) ushort_t Vt[64 * 64];     // [d][key], chunk c^=(d&7)^((d>>3)&7)
    __shared__ __align__(16) ushort_t Ps[4][16 * 64];  // per-wave [q][key], 16B-chunk c16^=q&7

    const int tid  = threadIdx.x;
    const int lane = tid & 63;
    const int w    = tid >> 6;
    const int bh = blockIdx.y;
    const int b = bh >> 4, h = bh & 15;

    const int l15 = lane & 15;
    const int g   = lane >> 4;

    const size_t rs = 3 * D_;
    const ushort_t* Qg = qkv + (size_t)b * S_ * rs + h * HD_;
    const ushort_t* Kg = Qg + D_;

    // staging geometry (constant per thread)
    const int skey = tid >> 3;          // 0..31 (+32 on pass 1)
    const int sc   = tid & 7;           // 16B chunk within row

    #pragma unroll
    for (int half = 0; half < 2; ++half) {
        const int qt = half ? blockIdx.x : (S_ / 64 - 1) - blockIdx.x;
        const int q0 = qt * 64;
        const int nkb = qt + 1;

        // Q B-frags (col=q=l15, k=g*8+e +kk*32), pre-scaled by SCALE_*log2e
        bf16x8 qf[2];
        {
            const int qrow = q0 + w * 16 + l15;
            #pragma unroll
            for (int kk = 0; kk < 2; ++kk) {
                bf16x8 tq = *(const bf16x8*)(Qg + (size_t)qrow * rs + kk * 32 + g * 8);
                #pragma unroll
                for (int e = 0; e < 8; ++e)
                    tq[e] = (short)f2bf(bf2f((ushort_t)tq[e]) * (SCALE_ * LOG2E_));
                qf[kk] = tq;
            }
        }

        float mrow = -1e30f, lrow = 0.f;
        f32x4 oacc[4] = {};   // d-frags; D: col=d=l15, row(q-local)=g*4+r

        // prologue: load KV tile 0 into regs
        bf16x8 kvreg[2], vvreg[2];
        #pragma unroll
        for (int pass = 0; pass < 2; ++pass) {
            const ushort_t* src = Kg + (size_t)(pass * 32 + skey) * rs + sc * 8;
            kvreg[pass] = *(const bf16x8*)src;
            vvreg[pass] = *(const bf16x8*)(src + D_);
        }

        for (int kb = 0; kb < nkb; ++kb) {
            __syncthreads();   // prior compute done reading LDS
            // ---- write staged regs -> LDS (K swizzled b128, V^T scatter) ----
            #pragma unroll
            for (int pass = 0; pass < 2; ++pass) {
                const int key = pass * 32 + skey;
                *(bf16x8*)&Ks[key * 64 + ((sc ^ (key & 7)) << 3)] = kvreg[pass];
                #pragma unroll
                for (int j = 0; j < 8; ++j) {
                    const int d  = sc * 8 + j;
                    const int cp = (key >> 3) ^ (d & 7) ^ ((d >> 3) & 7);
                    Vt[d * 64 + (cp << 3) + (key & 7)] = (ushort_t)vvreg[pass][j];
                }
            }
            // ---- prefetch next KV tile into regs (hidden under compute) ----
            if (kb + 1 < nkb) {
                #pragma unroll
                for (int pass = 0; pass < 2; ++pass) {
                    const ushort_t* src =
                        Kg + (size_t)((kb + 1) * 64 + pass * 32 + skey) * rs + sc * 8;
                    kvreg[pass] = *(const bf16x8*)src;
                    vvreg[pass] = *(const bf16x8*)(src + D_);
                }
            }
            __syncthreads();   // staging visible

            // ---- S^T = K Q^T (D[key][q]: col=q=l15, row=key=g*4+r) ----
            f32x4 sf[4] = {};
            __builtin_amdgcn_s_setprio(1);
            #pragma unroll
            for (int kk = 0; kk < 2; ++kk) {
                const int cc = kk * 4 + g;
                #pragma unroll
                for (int nf = 0; nf < 4; ++nf) {
                    const int keyr = nf * 16 + l15;
                    bf16x8 kf = *(const bf16x8*)&Ks[keyr * 64 + ((cc ^ (keyr & 7)) << 3)];
                    sf[nf] = __builtin_amdgcn_mfma_f32_16x16x32_bf16(kf, qf[kk], sf[nf], 0, 0, 0);
                }
            }
            __builtin_amdgcn_s_setprio(0);

            // ---- mask (only last kv-block can cross the diagonal) ----
            if (kb == nkb - 1) {
                const int q = q0 + w * 16 + l15;
                #pragma unroll
                for (int nf = 0; nf < 4; ++nf)
                    #pragma unroll
                    for (int r = 0; r < 4; ++r)
                        if (kb * 64 + nf * 16 + g * 4 + r > q) sf[nf][r] = -1e30f;
            }
            // ---- per-row max ----
            float mx = -1e30f;
            #pragma unroll
            for (int nf = 0; nf < 4; ++nf)
                #pragma unroll
                for (int r = 0; r < 4; ++r) mx = fmaxf(mx, sf[nf][r]);
            mx = fmaxf(mx, __shfl_xor(mx, 16));
            mx = fmaxf(mx, __shfl_xor(mx, 32));

            // ---- deferred-max rescale (T13, THR=8 in log2 units) ----
            if (!__all(mx - mrow <= 8.0f)) {
                const float mnew = fmaxf(mrow, mx);
                const float corr = fexp2(mrow - mnew);
                mrow = mnew;
                lrow *= corr;
                #pragma unroll
                for (int r = 0; r < 4; ++r) {
                    const float cr = __shfl(corr, g * 4 + r, 16);
                    #pragma unroll
                    for (int nf = 0; nf < 4; ++nf) oacc[nf][r] *= cr;
                }
            }

            // ---- P = exp2(S - m), row-sum, packed write to Ps ----
            {
                const int qrow = l15;
                float psum = 0.f;
                #pragma unroll
                for (int nf = 0; nf < 4; ++nf) {
                    const float p0 = fexp2(sf[nf][0] - mrow);
                    const float p1 = fexp2(sf[nf][1] - mrow);
                    const float p2 = fexp2(sf[nf][2] - mrow);
                    const float p3 = fexp2(sf[nf][3] - mrow);
                    psum += (p0 + p1) + (p2 + p3);
                    uint2 pk = make_uint2(cvt_pk_bf16(p0, p1), cvt_pk_bf16(p2, p3));
                    const int c16 = ((nf << 1) + (g >> 1)) ^ (qrow & 7);
                    *(uint2*)((char*)Ps[w] + qrow * 128 + c16 * 16 + (g & 1) * 8) = pk;
                }
                psum += __shfl_xor(psum, 16);
                psum += __shfl_xor(psum, 32);
                lrow += psum;
            }

            // ---- O += P V (A=P from Ps, B=V^T from Vt) ----
            #pragma unroll
            for (int kk = 0; kk < 2; ++kk) {
                const int cc = kk * 4 + g;
                const int qrow = l15;
                const int c16 = cc ^ (qrow & 7);
                bf16x8 pa = *(const bf16x8*)((const char*)Ps[w] + qrow * 128 + c16 * 16);
                __builtin_amdgcn_s_setprio(1);
                #pragma unroll
                for (int nf = 0; nf < 4; ++nf) {
                    const int dr  = nf * 16 + l15;
                    const int cvp = cc ^ (dr & 7) ^ ((dr >> 3) & 7);
                    bf16x8 vf = *(const bf16x8*)&Vt[dr * 64 + (cvp << 3)];
                    oacc[nf] = __builtin_amdgcn_mfma_f32_16x16x32_bf16(pa, vf, oacc[nf], 0, 0, 0);
                }
                __builtin_amdgcn_s_setprio(0);
            }
        }

        // ---- epilogue: O = acc / l (l lives at lane l15=row; broadcast) ----
        const float linv = 1.0f / lrow;
        #pragma unroll
        for (int r = 0; r < 4; ++r) {
            const float li = __shfl(linv, g * 4 + r, 16);
            const int q = q0 + w * 16 + g * 4 + r;
            ushort_t* op = out + (size_t)(b * S_ + q) * D_ + h * HD_;
            #pragma unroll
            for (int nf = 0; nf < 4; ++nf)
                op[nf * 16 + l15] = f2bf(oacc[nf][r] * li);
        }
    }
}

// ---------------------------------------------------------------------------
// launch
// ---------------------------------------------------------------------------
extern "C" void kernel_launch(void* const* d_in, const int* in_sizes, int n_in,
                              void* d_out, int out_size, void* d_ws, size_t ws_size,
                              hipStream_t stream)
{
    const float* x   = (const float*)d_in[0];
    const float* Wq  = (const float*)d_in[1];
    const float* bq  = (const float*)d_in[2];
    const float* Wk  = (const float*)d_in[3];
    const float* bk  = (const float*)d_in[4];
    const float* Wv  = (const float*)d_in[5];
    const float* bv  = (const float*)d_in[6];
    const float* Wo  = (const float*)d_in[7];
    const float* bo  = (const float*)d_in[8];
    const float* g1  = (const float*)d_in[9];
    const float* be1 = (const float*)d_in[10];
    const float* g2  = (const float*)d_in[11];
    const float* be2 = (const float*)d_in[12];
    const float* W1  = (const float*)d_in[13];
    const float* b1  = (const float*)d_in[14];
    const float* W2  = (const float*)d_in[15];
    const float* b2  = (const float*)d_in[16];
    float* out = (float*)d_out;

    char* ws = (char*)d_ws;
    size_t o = 0;
    auto alloc = [&](size_t bytes) { size_t r = o; o = (o + bytes + 255) & ~(size_t)255; return r; };
    ushort_t* Wqkvt = (ushort_t*)(ws + alloc((size_t)3 * D_ * D_ * 2));   // [3072][1024]
    ushort_t* Wot   = (ushort_t*)(ws + alloc((size_t)D_ * D_ * 2));      // [1024][1024]
    ushort_t* W1t   = (ushort_t*)(ws + alloc((size_t)DFF_ * D_ * 2));    // [4096][1024]
    ushort_t* W2t   = (ushort_t*)(ws + alloc((size_t)D_ * DFF_ * 2));    // [1024][4096]
    float*    bqkv  = (float*)(ws + alloc((size_t)3 * D_ * 4));
    ushort_t* lnbuf = (ushort_t*)(ws + alloc((size_t)M_ * D_ * 2));      // ln1 then ln2
    ushort_t* bigbuf= (ushort_t*)(ws + alloc((size_t)M_ * DFF_ * 2));    // qkv then ffn-hidden
    ushort_t* attnb = (ushort_t*)(ws + alloc((size_t)M_ * D_ * 2));
    float*    x1    = (float*)(ws + alloc((size_t)M_ * D_ * 4));

    dim3 tblock(32, 8);
    transpose_cast_kernel<<<dim3(D_/32, D_/32), tblock, 0, stream>>>(Wq, Wqkvt,            D_, D_);
    transpose_cast_kernel<<<dim3(D_/32, D_/32), tblock, 0, stream>>>(Wk, Wqkvt + D_*D_,    D_, D_);
    transpose_cast_kernel<<<dim3(D_/32, D_/32), tblock, 0, stream>>>(Wv, Wqkvt + 2*D_*D_,  D_, D_);
    transpose_cast_kernel<<<dim3(D_/32, D_/32), tblock, 0, stream>>>(Wo, Wot,              D_, D_);
    transpose_cast_kernel<<<dim3(DFF_/32, D_/32), tblock, 0, stream>>>(W1, W1t,            D_, DFF_);
    transpose_cast_kernel<<<dim3(D_/32, DFF_/32), tblock, 0, stream>>>(W2, W2t,            DFF_, D_);
    concat_bias_kernel<<<12, 256, 0, stream>>>(bq, bk, bv, bqkv);

    // ln1
    ln_kernel<<<M_, 256, 0, stream>>>(x, g1, be1, lnbuf);
    // qkv = ln1 @ Wqkv + bqkv          [8192][3072] bf16   grid 32*24=768
    gemm_bt3_kernel<0, 256><<<(M_/256)*(3*D_/128), 512, 0, stream>>>(
        lnbuf, Wqkvt, bqkv, nullptr, bigbuf, M_, 3*D_, D_, 3*D_/128);
    // flash attention (paired q-tiles)  [8192][1024] bf16
    fattn_kernel<<<dim3(S_/128, B_*H_), 256, 0, stream>>>(bigbuf, attnb);
    // x1 = x + RES*(attn @ Wo + bo)     [8192][1024] fp32  grid 64*8=512
    gemm_bt3_kernel<2, 128><<<(M_/128)*(D_/128), 256, 0, stream>>>(
        attnb, Wot, bo, x, x1, M_, D_, D_, D_/128);
    // ln2
    ln_kernel<<<M_, 256, 0, stream>>>(x1, g2, be2, lnbuf);
    // ffh = relu(ln2 @ W1 + b1)         [8192][4096] bf16  grid 32*32=1024
    gemm_bt3_kernel<1, 256><<<(M_/256)*(DFF_/128), 512, 0, stream>>>(
        lnbuf, W1t, b1, nullptr, bigbuf, M_, DFF_, D_, DFF_/128);
    // out = x1 + RES*(ffh @ W2 + b2)    [8192][1024] fp32  grid 64*8=512
    gemm_bt3_kernel<2, 128><<<(M_/128)*(D_/128), 256, 0, stream>>>(
        bigbuf, W2t, b2, x1, out, M_, D_, DFF_, D_/128);
}